// Round 1
// baseline (510.168 us; speedup 1.0000x reference)
//
#include <hip/hip_runtime.h>
#include <hip/hip_bf16.h>

// Problem constants
#define BB 128
#define NN 256
#define CC 192
#define HH 8
#define HD 24
#define NWIN 16
#define MROWS (BB * NN)          // 32768
#define QKVN (3 * CC)            // 576
#define PERHEAD (NN * HD)        // 6144 floats per (b,h)
#define QS (BB * HH * NN * HD)   // 6291456 floats per tensor

// ---------------------------------------------------------------------------
// Kernel 1: qkv = x @ qkv_w.T  -> scatter to q,k,v each (B,H,N,hd)
// Tiled fp32 GEMM: 64x64 tile, BK=16, 256 threads, 4x4 register tile.
// ---------------------------------------------------------------------------
__global__ __launch_bounds__(256) void qkv_gemm_kernel(
    const float* __restrict__ x,    // (32768, 192)
    const float* __restrict__ w,    // (576, 192)
    float* __restrict__ qb, float* __restrict__ kb, float* __restrict__ vb)
{
    __shared__ __align__(16) float As[16][68];  // [kk][m], pad 68 -> 2-way max
    __shared__ __align__(16) float Bs[16][68];  // [kk][c]
    const int tid = threadIdx.x;
    const int bm = blockIdx.x * 64;
    const int bn = blockIdx.y * 64;
    const int tm = tid >> 4;        // 0..15 (row quad)
    const int tn = tid & 15;        // 0..15 (col quad)
    const int lk = tid & 15;        // load: k within 16
    const int lr = tid >> 4;        // load: row within 16

    float acc[4][4] = {};

    for (int k0 = 0; k0 < 192; k0 += 16) {
        #pragma unroll
        for (int i = 0; i < 4; ++i)
            As[lk][lr + 16 * i] = x[(bm + lr + 16 * i) * 192 + k0 + lk];
        #pragma unroll
        for (int i = 0; i < 4; ++i)
            Bs[lk][lr + 16 * i] = w[(bn + lr + 16 * i) * 192 + k0 + lk];
        __syncthreads();
        #pragma unroll
        for (int kk = 0; kk < 16; ++kk) {
            float4 av = *reinterpret_cast<const float4*>(&As[kk][tm * 4]);
            float4 bv = *reinterpret_cast<const float4*>(&Bs[kk][tn * 4]);
            float a4[4] = {av.x, av.y, av.z, av.w};
            float b4[4] = {bv.x, bv.y, bv.z, bv.w};
            #pragma unroll
            for (int i = 0; i < 4; ++i)
                #pragma unroll
                for (int j = 0; j < 4; ++j)
                    acc[i][j] += a4[i] * b4[j];
        }
        __syncthreads();
    }

    // scatter: column c of (576) splits as (t3, h, d) = (c/192, (c%192)/24, c%24)
    #pragma unroll
    for (int i = 0; i < 4; ++i) {
        int m = bm + tm * 4 + i;
        int b = m >> 8, n = m & 255;
        #pragma unroll
        for (int j = 0; j < 4; ++j) {
            int c = bn + tn * 4 + j;
            int t3 = c / 192;
            int rem = c - t3 * 192;
            int h = rem / 24;
            int d = rem - h * 24;
            float* dst = (t3 == 0) ? qb : (t3 == 1) ? kb : vb;
            dst[(((b * HH + h) * NN) + n) * HD + d] = acc[i][j];
        }
    }
}

// ---------------------------------------------------------------------------
// Kernel 2: fused attention per (b, h, 64-row tile of Q)
// S = scale*Q@K^T + rel[h] + mask[b%16]; softmax; out = P@V -> (B,N,C) layout
// ---------------------------------------------------------------------------
__global__ __launch_bounds__(256) void attn_kernel(
    const float* __restrict__ qb, const float* __restrict__ kb,
    const float* __restrict__ vb,
    const float* __restrict__ rel, const float* __restrict__ maskp,
    float* __restrict__ aout)
{
    __shared__ __align__(16) float Ks[NN * HD];     // 24 KB
    __shared__ __align__(16) float Vs[NN * HD];     // 24 KB
    __shared__ float S[64 * 257];                   // 64.25 KB, stride 257 -> conflict-free
    __shared__ float inv[64];

    const int bid = blockIdx.x;
    const int rt = bid & 3;             // row tile (64 rows)
    const int h  = (bid >> 2) & 7;
    const int b  = bid >> 5;
    const int wi = b & (NWIN - 1);      // mask window index = b % 16
    const int tid = threadIdx.x;

    const float* kp = kb + (b * HH + h) * PERHEAD;
    const float* vp = vb + (b * HH + h) * PERHEAD;

    // cooperative K,V load (float4)
    {
        const float4* kp4 = reinterpret_cast<const float4*>(kp);
        const float4* vp4 = reinterpret_cast<const float4*>(vp);
        float4* ks4 = reinterpret_cast<float4*>(Ks);
        float4* vs4 = reinterpret_cast<float4*>(Vs);
        for (int i = tid; i < PERHEAD / 4; i += 256) {
            ks4[i] = kp4[i];
            vs4[i] = vp4[i];
        }
    }

    // each thread owns Q row r (duplicated across the 4 column-groups)
    const int r = tid & 63;
    const int cg = tid >> 6;
    const int n = rt * 64 + r;
    const float scale = 0.20412414523193154f;  // 24^-0.5
    float4 q4[6];
    {
        const float4* qp4 = reinterpret_cast<const float4*>(
            qb + (((b * HH + h) * NN) + n) * HD);
        #pragma unroll
        for (int dq = 0; dq < 6; ++dq) {
            float4 v = qp4[dq];
            v.x *= scale; v.y *= scale; v.z *= scale; v.w *= scale;
            q4[dq] = v;
        }
    }
    __syncthreads();

    // phase 1: scores. wave-uniform c => Ks broadcast; S stride 257 write
    for (int cc = 0; cc < 64; ++cc) {
        int c = cg * 64 + cc;
        const float4* kr4 = reinterpret_cast<const float4*>(Ks + c * HD);
        float s = 0.f;
        #pragma unroll
        for (int dq = 0; dq < 6; ++dq) {
            float4 kv = kr4[dq];
            s += q4[dq].x * kv.x + q4[dq].y * kv.y +
                 q4[dq].z * kv.z + q4[dq].w * kv.w;
        }
        S[r * 257 + c] = s;
    }
    __syncthreads();

    // phase 1.5: bias add, coalesced float4 global reads
    {
        const float4* relp4 = reinterpret_cast<const float4*>(
            rel + h * (NN * NN) + rt * 64 * NN);
        const float4* mp4 = reinterpret_cast<const float4*>(
            maskp + wi * (NN * NN) + rt * 64 * NN);
        for (int i = tid; i < 64 * 64; i += 256) {
            int rr = i >> 6;
            int c4 = (i & 63) * 4;
            float4 rv = relp4[i];
            float4 mv = mp4[i];
            float* sp = S + rr * 257 + c4;
            sp[0] += rv.x + mv.x;
            sp[1] += rv.y + mv.y;
            sp[2] += rv.z + mv.z;
            sp[3] += rv.w + mv.w;
        }
    }
    __syncthreads();

    // phase 2: softmax, 4 lanes per row
    {
        int r2 = tid >> 2, qt = tid & 3;
        float* row = S + r2 * 257 + qt * 64;
        float mx = -1e30f;
        for (int j = 0; j < 64; ++j) mx = fmaxf(mx, row[j]);
        mx = fmaxf(mx, __shfl_xor(mx, 1));
        mx = fmaxf(mx, __shfl_xor(mx, 2));
        float sm = 0.f;
        for (int j = 0; j < 64; ++j) {
            float e = __expf(row[j] - mx);
            row[j] = e;
            sm += e;
        }
        sm += __shfl_xor(sm, 1);
        sm += __shfl_xor(sm, 2);
        if (qt == 0) inv[r2] = 1.0f / sm;
    }
    __syncthreads();

    // phase 3: PV. thread -> (row rr, dim-quad dq); V broadcast float4
    {
        int rr = tid & 63;
        int dq0 = tid >> 6;
        const float* srow = S + rr * 257;
        float isum = inv[rr];
        float* op = aout + ((b * NN + rt * 64 + rr) * CC) + h * HD;
        for (int dq = dq0; dq < 6; dq += 4) {
            const float4* vq = reinterpret_cast<const float4*>(Vs) + dq;
            float4 a4 = {0.f, 0.f, 0.f, 0.f};
            for (int c = 0; c < 256; ++c) {
                float p = srow[c];
                float4 vv = vq[c * 6];
                a4.x += p * vv.x; a4.y += p * vv.y;
                a4.z += p * vv.z; a4.w += p * vv.w;
            }
            a4.x *= isum; a4.y *= isum; a4.z *= isum; a4.w *= isum;
            *reinterpret_cast<float4*>(op + dq * 4) = a4;
        }
    }
}

// ---------------------------------------------------------------------------
// Kernel 3: out = aout @ proj_w.T + proj_b   (32768x192x192)
// ---------------------------------------------------------------------------
__global__ __launch_bounds__(256) void proj_gemm_kernel(
    const float* __restrict__ a,    // (32768, 192)
    const float* __restrict__ w,    // (192, 192)
    const float* __restrict__ bias, // (192,)
    float* __restrict__ out)
{
    __shared__ __align__(16) float As[16][68];
    __shared__ __align__(16) float Bs[16][68];
    const int tid = threadIdx.x;
    const int bm = blockIdx.x * 64;
    const int bn = blockIdx.y * 64;
    const int tm = tid >> 4;
    const int tn = tid & 15;
    const int lk = tid & 15;
    const int lr = tid >> 4;

    float acc[4][4] = {};

    for (int k0 = 0; k0 < 192; k0 += 16) {
        #pragma unroll
        for (int i = 0; i < 4; ++i)
            As[lk][lr + 16 * i] = a[(bm + lr + 16 * i) * 192 + k0 + lk];
        #pragma unroll
        for (int i = 0; i < 4; ++i)
            Bs[lk][lr + 16 * i] = w[(bn + lr + 16 * i) * 192 + k0 + lk];
        __syncthreads();
        #pragma unroll
        for (int kk = 0; kk < 16; ++kk) {
            float4 av = *reinterpret_cast<const float4*>(&As[kk][tm * 4]);
            float4 bv = *reinterpret_cast<const float4*>(&Bs[kk][tn * 4]);
            float a4[4] = {av.x, av.y, av.z, av.w};
            float b4[4] = {bv.x, bv.y, bv.z, bv.w};
            #pragma unroll
            for (int i = 0; i < 4; ++i)
                #pragma unroll
                for (int j = 0; j < 4; ++j)
                    acc[i][j] += a4[i] * b4[j];
        }
        __syncthreads();
    }

    #pragma unroll
    for (int i = 0; i < 4; ++i) {
        int m = bm + tm * 4 + i;
        #pragma unroll
        for (int j = 0; j < 4; ++j) {
            int c = bn + tn * 4 + j;
            out[m * 192 + c] = acc[i][j] + bias[c];
        }
    }
}

extern "C" void kernel_launch(void* const* d_in, const int* in_sizes, int n_in,
                              void* d_out, int out_size, void* d_ws, size_t ws_size,
                              hipStream_t stream) {
    const float* x      = (const float*)d_in[0];
    const float* rel    = (const float*)d_in[1];
    const float* maskp  = (const float*)d_in[2];
    const float* qkv_w  = (const float*)d_in[3];
    const float* proj_w = (const float*)d_in[4];
    const float* proj_b = (const float*)d_in[5];
    float* out = (float*)d_out;

    float* ws = (float*)d_ws;
    float* qb = ws;
    float* kb = ws + (size_t)QS;
    float* vb = ws + (size_t)QS * 2;
    float* ab = ws + (size_t)QS * 3;

    qkv_gemm_kernel<<<dim3(512, 9), 256, 0, stream>>>(x, qkv_w, qb, kb, vb);
    attn_kernel<<<dim3(BB * HH * 4), 256, 0, stream>>>(qb, kb, vb, rel, maskp, ab);
    proj_gemm_kernel<<<dim3(512, 3), 256, 0, stream>>>(ab, proj_w, proj_b, out);
}

// Round 2
// 247.578 us; speedup vs baseline: 2.0606x; 2.0606x over previous
//
#include <hip/hip_runtime.h>
#include <hip/hip_bf16.h>

#define BB 128
#define NN 256
#define CC 192
#define HH 8
#define HD 24
#define HD2 32
#define NWIN 16

typedef __bf16 bf16x8 __attribute__((ext_vector_type(8)));
typedef float f32x4 __attribute__((ext_vector_type(4)));

#define QB_BYTES (size_t)(BB * HH * NN * HD2 * 2)   // 16,777,216

__device__ inline unsigned short f2bf(float x) {
    unsigned int u = __float_as_uint(x);
    unsigned int r = (u + 0x7FFFu + ((u >> 16) & 1u)) >> 16;
    return (unsigned short)r;
}

// ---------------------------------------------------------------------------
// Kernel 1: qkv = x @ qkv_w.T (fp32 compute), epilogue -> bf16 q,k (B,H,N,32)
// with q pre-scaled by 24^-0.5, and v transposed (B,H,32,256).
// ---------------------------------------------------------------------------
__global__ __launch_bounds__(256) void qkv_gemm_kernel(
    const float* __restrict__ x,    // (32768, 192)
    const float* __restrict__ w,    // (576, 192)
    unsigned short* __restrict__ qb, unsigned short* __restrict__ kb,
    unsigned short* __restrict__ vt)
{
    __shared__ __align__(16) float As[16][68];
    __shared__ __align__(16) float Bs[16][68];
    const int tid = threadIdx.x;
    const int bm = blockIdx.x * 64;
    const int bn = blockIdx.y * 64;
    const int tm = tid >> 4;
    const int tn = tid & 15;
    const int lk = tid & 15;
    const int lr = tid >> 4;

    float acc[4][4] = {};

    for (int k0 = 0; k0 < 192; k0 += 16) {
        #pragma unroll
        for (int i = 0; i < 4; ++i)
            As[lk][lr + 16 * i] = x[(bm + lr + 16 * i) * 192 + k0 + lk];
        #pragma unroll
        for (int i = 0; i < 4; ++i)
            Bs[lk][lr + 16 * i] = w[(bn + lr + 16 * i) * 192 + k0 + lk];
        __syncthreads();
        #pragma unroll
        for (int kk = 0; kk < 16; ++kk) {
            float4 av = *reinterpret_cast<const float4*>(&As[kk][tm * 4]);
            float4 bv = *reinterpret_cast<const float4*>(&Bs[kk][tn * 4]);
            float a4[4] = {av.x, av.y, av.z, av.w};
            float b4[4] = {bv.x, bv.y, bv.z, bv.w};
            #pragma unroll
            for (int i = 0; i < 4; ++i)
                #pragma unroll
                for (int j = 0; j < 4; ++j)
                    acc[i][j] += a4[i] * b4[j];
        }
        __syncthreads();
    }

    const float SCALE = 0.20412414523193154f;  // 24^-0.5
    #pragma unroll
    for (int i = 0; i < 4; ++i) {
        int m = bm + tm * 4 + i;
        int bbi = m >> 8, n = m & 255;
        #pragma unroll
        for (int j = 0; j < 4; ++j) {
            int c = bn + tn * 4 + j;
            int t3 = c / 192;
            int rem = c - t3 * 192;
            int hh = rem / 24;
            int d = rem - hh * 24;
            size_t bh = (size_t)(bbi * HH + hh);
            float v = acc[i][j];
            if (t3 == 0)      qb[(bh * NN + n) * HD2 + d] = f2bf(v * SCALE);
            else if (t3 == 1) kb[(bh * NN + n) * HD2 + d] = f2bf(v);
            else              vt[(bh * HD2 + d) * NN + n] = f2bf(v);
        }
    }
}

// ---------------------------------------------------------------------------
// Kernel 2: MFMA attention. 1 block per (b,h), 8 waves x 32 q-rows.
// S^T = mfma(K, Q); bias+softmax in-register; out^T = mfma(V^T, P) with
// per-wave LDS bounce of P in [q][k] layout.
// ---------------------------------------------------------------------------
#define KSTR 40    // K LDS row stride (ushorts): 80B, 2-way-free banks
#define VSTR 272   // Vt LDS row stride: 544B, 16B aligned
#define PSTR 80    // P LDS row stride: 160B, 16B aligned

__global__ __launch_bounds__(512) void attn_mfma_kernel(
    const unsigned short* __restrict__ qb, const unsigned short* __restrict__ kb,
    const unsigned short* __restrict__ vt,
    const float* __restrict__ rel, const float* __restrict__ maskp,
    float* __restrict__ ab)
{
    __shared__ __align__(16) unsigned short Kl[NN * KSTR];       // 20480 B
    __shared__ __align__(16) unsigned short Vl[HD2 * VSTR];      // 17408 B
    __shared__ __align__(16) unsigned short Pw[8][32 * PSTR];    // 40960 B

    const int tid = threadIdx.x;
    const int w  = tid >> 6;
    const int l  = tid & 63;
    const int lq = l & 15;
    const int g  = l >> 4;
    const int bid = blockIdx.x;
    const int h = bid & 7, b = bid >> 3;
    const int wi = b & (NWIN - 1);

    const unsigned short* kp = kb + (size_t)(b * HH + h) * NN * HD2;
    const unsigned short* vp = vt + (size_t)(b * HH + h) * HD2 * NN;
    const unsigned short* qp = qb + (size_t)(b * HH + h) * NN * HD2;

    // stage K: 256 rows x 64B -> stride 80B
    for (int i = tid; i < 1024; i += 512) {
        int r = i >> 2, c = i & 3;
        *reinterpret_cast<uint4*>(&Kl[r * KSTR + c * 8]) =
            *reinterpret_cast<const uint4*>(kp + r * HD2 + c * 8);
    }
    // stage Vt: 32 rows x 512B -> stride 544B
    for (int i = tid; i < 1024; i += 512) {
        int r = i >> 5, c = i & 31;
        *reinterpret_cast<uint4*>(&Vl[r * VSTR + c * 8]) =
            *reinterpret_cast<const uint4*>(vp + r * NN + c * 8);
    }

    // Q fragments (B operand): rows q = w*32 + t*16 + lq, 16B at chunk g
    bf16x8 qf[2];
    #pragma unroll
    for (int t = 0; t < 2; ++t)
        qf[t] = *reinterpret_cast<const bf16x8*>(
            qp + (w * 32 + t * 16 + lq) * HD2 + g * 8);

    __syncthreads();

    // QK^T: acc[t][f][jr] = S^T[k = 16f+4g+jr][q = 32w+16t+lq]
    f32x4 acc[2][16];
    #pragma unroll
    for (int t = 0; t < 2; ++t)
        #pragma unroll
        for (int f = 0; f < 16; ++f)
            acc[t][f] = (f32x4){0.f, 0.f, 0.f, 0.f};

    #pragma unroll
    for (int f = 0; f < 16; ++f) {
        bf16x8 kf = *reinterpret_cast<const bf16x8*>(&Kl[(f * 16 + lq) * KSTR + g * 8]);
        acc[0][f] = __builtin_amdgcn_mfma_f32_16x16x32_bf16(kf, qf[0], acc[0][f], 0, 0, 0);
        acc[1][f] = __builtin_amdgcn_mfma_f32_16x16x32_bf16(kf, qf[1], acc[1][f], 0, 0, 0);
    }

    // bias: + rel[h][q][k] + mask[wi][q][k], float4 over jr (k contiguous)
    #pragma unroll
    for (int t = 0; t < 2; ++t) {
        int q = w * 32 + t * 16 + lq;
        const float* rp = rel + ((size_t)h * NN + q) * NN;
        const float* mp = maskp + ((size_t)wi * NN + q) * NN;
        #pragma unroll
        for (int f = 0; f < 16; ++f) {
            int k0 = f * 16 + g * 4;
            float4 rv = *reinterpret_cast<const float4*>(rp + k0);
            float4 mv = *reinterpret_cast<const float4*>(mp + k0);
            acc[t][f][0] += rv.x + mv.x;
            acc[t][f][1] += rv.y + mv.y;
            acc[t][f][2] += rv.z + mv.z;
            acc[t][f][3] += rv.w + mv.w;
        }
    }

    // softmax over k (per-lane 64 vals + shfl_xor 16,32 across g groups)
    float inv[2];
    #pragma unroll
    for (int t = 0; t < 2; ++t) {
        float m = -3.0e38f;
        #pragma unroll
        for (int f = 0; f < 16; ++f)
            #pragma unroll
            for (int jr = 0; jr < 4; ++jr)
                m = fmaxf(m, acc[t][f][jr]);
        m = fmaxf(m, __shfl_xor(m, 16));
        m = fmaxf(m, __shfl_xor(m, 32));
        float s = 0.f;
        #pragma unroll
        for (int f = 0; f < 16; ++f)
            #pragma unroll
            for (int jr = 0; jr < 4; ++jr) {
                float e = __expf(acc[t][f][jr] - m);
                acc[t][f][jr] = e;
                s += e;
            }
        s += __shfl_xor(s, 16);
        s += __shfl_xor(s, 32);
        inv[t] = 1.0f / s;
    }

    // PV: out^T = V^T @ P^T, k chunks of 64 through per-wave LDS bounce
    f32x4 oacc[2][2];  // [dt][t]
    #pragma unroll
    for (int dt = 0; dt < 2; ++dt)
        #pragma unroll
        for (int t = 0; t < 2; ++t)
            oacc[dt][t] = (f32x4){0.f, 0.f, 0.f, 0.f};

    for (int c = 0; c < 4; ++c) {
        // write P chunk: row q_local = 16t+lq, k_local = 16fp+4g+jr
        #pragma unroll
        for (int t = 0; t < 2; ++t)
            #pragma unroll
            for (int fp = 0; fp < 4; ++fp) {
                int f = c * 4 + fp;
                uint2 pk;
                pk.x = (unsigned int)f2bf(acc[t][f][0]) |
                       ((unsigned int)f2bf(acc[t][f][1]) << 16);
                pk.y = (unsigned int)f2bf(acc[t][f][2]) |
                       ((unsigned int)f2bf(acc[t][f][3]) << 16);
                *reinterpret_cast<uint2*>(
                    &Pw[w][(t * 16 + lq) * PSTR + fp * 16 + g * 4]) = pk;
            }
        __asm__ volatile("s_waitcnt lgkmcnt(0)" ::: "memory");
        #pragma unroll
        for (int k2 = 0; k2 < 2; ++k2) {
            bf16x8 bp0 = *reinterpret_cast<const bf16x8*>(
                &Pw[w][(0 * 16 + lq) * PSTR + k2 * 32 + g * 8]);
            bf16x8 bp1 = *reinterpret_cast<const bf16x8*>(
                &Pw[w][(1 * 16 + lq) * PSTR + k2 * 32 + g * 8]);
            #pragma unroll
            for (int dt = 0; dt < 2; ++dt) {
                bf16x8 av = *reinterpret_cast<const bf16x8*>(
                    &Vl[(dt * 16 + lq) * VSTR + c * 64 + k2 * 32 + g * 8]);
                oacc[dt][0] = __builtin_amdgcn_mfma_f32_16x16x32_bf16(av, bp0, oacc[dt][0], 0, 0, 0);
                oacc[dt][1] = __builtin_amdgcn_mfma_f32_16x16x32_bf16(av, bp1, oacc[dt][1], 0, 0, 0);
            }
        }
    }

    // epilogue: out^T[d = 16dt+4g+jr][q = 32w+16t+lq] * inv -> ab[(b,q)][h*24+d]
    #pragma unroll
    for (int t = 0; t < 2; ++t) {
        int qg = b * NN + w * 32 + t * 16 + lq;
        float* op = ab + (size_t)qg * CC + h * HD;
        #pragma unroll
        for (int dt = 0; dt < 2; ++dt) {
            int d0 = dt * 16 + g * 4;
            if (d0 < HD) {
                float4 o;
                o.x = oacc[dt][t][0] * inv[t];
                o.y = oacc[dt][t][1] * inv[t];
                o.z = oacc[dt][t][2] * inv[t];
                o.w = oacc[dt][t][3] * inv[t];
                *reinterpret_cast<float4*>(op + d0) = o;
            }
        }
    }
}

// ---------------------------------------------------------------------------
// Kernel 3: out = ab @ proj_w.T + proj_b (fp32, unchanged)
// ---------------------------------------------------------------------------
__global__ __launch_bounds__(256) void proj_gemm_kernel(
    const float* __restrict__ a,
    const float* __restrict__ w,
    const float* __restrict__ bias,
    float* __restrict__ out)
{
    __shared__ __align__(16) float As[16][68];
    __shared__ __align__(16) float Bs[16][68];
    const int tid = threadIdx.x;
    const int bm = blockIdx.x * 64;
    const int bn = blockIdx.y * 64;
    const int tm = tid >> 4;
    const int tn = tid & 15;
    const int lk = tid & 15;
    const int lr = tid >> 4;

    float acc[4][4] = {};

    for (int k0 = 0; k0 < 192; k0 += 16) {
        #pragma unroll
        for (int i = 0; i < 4; ++i)
            As[lk][lr + 16 * i] = a[(bm + lr + 16 * i) * 192 + k0 + lk];
        #pragma unroll
        for (int i = 0; i < 4; ++i)
            Bs[lk][lr + 16 * i] = w[(bn + lr + 16 * i) * 192 + k0 + lk];
        __syncthreads();
        #pragma unroll
        for (int kk = 0; kk < 16; ++kk) {
            float4 av = *reinterpret_cast<const float4*>(&As[kk][tm * 4]);
            float4 bv = *reinterpret_cast<const float4*>(&Bs[kk][tn * 4]);
            float a4[4] = {av.x, av.y, av.z, av.w};
            float b4[4] = {bv.x, bv.y, bv.z, bv.w};
            #pragma unroll
            for (int i = 0; i < 4; ++i)
                #pragma unroll
                for (int j = 0; j < 4; ++j)
                    acc[i][j] += a4[i] * b4[j];
        }
        __syncthreads();
    }

    #pragma unroll
    for (int i = 0; i < 4; ++i) {
        int m = bm + tm * 4 + i;
        #pragma unroll
        for (int j = 0; j < 4; ++j) {
            int c = bn + tn * 4 + j;
            out[m * 192 + c] = acc[i][j] + bias[c];
        }
    }
}

extern "C" void kernel_launch(void* const* d_in, const int* in_sizes, int n_in,
                              void* d_out, int out_size, void* d_ws, size_t ws_size,
                              hipStream_t stream) {
    const float* x      = (const float*)d_in[0];
    const float* rel    = (const float*)d_in[1];
    const float* maskp  = (const float*)d_in[2];
    const float* qkv_w  = (const float*)d_in[3];
    const float* proj_w = (const float*)d_in[4];
    const float* proj_b = (const float*)d_in[5];
    float* out = (float*)d_out;

    unsigned char* wsb = (unsigned char*)d_ws;
    unsigned short* qbp = (unsigned short*)(wsb);
    unsigned short* kbp = (unsigned short*)(wsb + QB_BYTES);
    unsigned short* vtp = (unsigned short*)(wsb + 2 * QB_BYTES);
    float*          abp = (float*)(wsb + 3 * QB_BYTES);

    // zero Q pads (d=24..31) so padded-K garbage contributes 0 to S
    hipMemsetAsync(qbp, 0, QB_BYTES, stream);

    qkv_gemm_kernel<<<dim3(512, 9), 256, 0, stream>>>(x, qkv_w, qbp, kbp, vtp);
    attn_mfma_kernel<<<dim3(BB * HH), 512, 0, stream>>>(qbp, kbp, vtp, rel, maskp, abp);
    proj_gemm_kernel<<<dim3(512, 3), 256, 0, stream>>>(abp, proj_w, proj_b, out);
}

// Round 3
// 147.941 us; speedup vs baseline: 3.4485x; 1.6735x over previous
//
#include <hip/hip_runtime.h>
#include <hip/hip_bf16.h>

#define BB 128
#define NN 256
#define CC 192
#define HH 8
#define HD 24
#define HD2 32
#define NWIN 16

typedef __bf16 bf16x8 __attribute__((ext_vector_type(8)));
typedef float f32x4 __attribute__((ext_vector_type(4)));

#define QB_BYTES (size_t)(BB * HH * NN * HD2 * 2)   // 16,777,216
#define XB_BYTES (size_t)(BB * NN * CC * 2)         // 12,582,912
#define AB_BYTES (size_t)(BB * NN * CC * 2)         // 12,582,912
#define WQ_BYTES (size_t)(3 * CC * CC * 2)          // 221,184

__device__ inline unsigned short f2bf(float x) {
    unsigned int u = __float_as_uint(x);
    unsigned int r = (u + 0x7FFFu + ((u >> 16) & 1u)) >> 16;
    return (unsigned short)r;
}

// ---------------------------------------------------------------------------
// Kernel 0: fp32 -> bf16 conversion of x, qkv_w, proj_w (one pass)
// ---------------------------------------------------------------------------
#define NX4  1572864   // 6291456/4
#define NWQ4 27648     // 110592/4
#define NWP4 9216      // 36864/4

__global__ __launch_bounds__(256) void convert_kernel(
    const float* __restrict__ x, const float* __restrict__ wq,
    const float* __restrict__ wp,
    unsigned short* __restrict__ xb, unsigned short* __restrict__ wqb,
    unsigned short* __restrict__ wpb)
{
    int i = blockIdx.x * 256 + threadIdx.x;
    const float* src; unsigned short* dst; int j;
    if (i < NX4)              { src = x;  dst = xb;  j = i; }
    else if (i < NX4 + NWQ4)  { src = wq; dst = wqb; j = i - NX4; }
    else                      { src = wp; dst = wpb; j = i - NX4 - NWQ4; }
    float4 v = reinterpret_cast<const float4*>(src)[j];
    ushort4 o;
    o.x = f2bf(v.x); o.y = f2bf(v.y); o.z = f2bf(v.z); o.w = f2bf(v.w);
    reinterpret_cast<ushort4*>(dst)[j] = o;
}

// ---------------------------------------------------------------------------
// Kernel 1: qkv = xb @ wq^T (bf16 MFMA, full K=192 in LDS, 128x64 tile)
// epilogue scatters to q (scaled, B,H,N,32), k (B,H,N,32), v^T (B,H,32,256)
// ---------------------------------------------------------------------------
__global__ __launch_bounds__(256) void qkv_mfma_kernel(
    const unsigned short* __restrict__ xb, const unsigned short* __restrict__ wqb,
    unsigned short* __restrict__ qb, unsigned short* __restrict__ kb,
    unsigned short* __restrict__ vt)
{
    __shared__ __align__(16) unsigned short Xs[128 * 200];  // 51200 B
    __shared__ __align__(16) unsigned short Ws[64 * 200];   // 25600 B

    const int tid = threadIdx.x;
    const int bm = blockIdx.x * 128, bn = blockIdx.y * 64;

    // stage X tile: thread -> (row tid>>1, half tid&1), 96 contiguous ushorts
    {
        const unsigned short* src = xb + (size_t)(bm + (tid >> 1)) * 192 + (tid & 1) * 96;
        unsigned short* dst = &Xs[(tid >> 1) * 200 + (tid & 1) * 96];
        #pragma unroll
        for (int i = 0; i < 12; ++i)
            *reinterpret_cast<uint4*>(dst + i * 8) =
                *reinterpret_cast<const uint4*>(src + i * 8);
    }
    // stage W tile: thread -> (row tid>>2, quarter tid&3), 48 ushorts
    {
        const unsigned short* src = wqb + (size_t)(bn + (tid >> 2)) * 192 + (tid & 3) * 48;
        unsigned short* dst = &Ws[(tid >> 2) * 200 + (tid & 3) * 48];
        #pragma unroll
        for (int i = 0; i < 6; ++i)
            *reinterpret_cast<uint4*>(dst + i * 8) =
                *reinterpret_cast<const uint4*>(src + i * 8);
    }
    __syncthreads();

    const int w = tid >> 6, l = tid & 63, lq = l & 15, g = l >> 4;
    const int wm = w >> 1, wn = w & 1;

    f32x4 acc[4][2];
    #pragma unroll
    for (int s = 0; s < 4; ++s)
        #pragma unroll
        for (int t = 0; t < 2; ++t)
            acc[s][t] = (f32x4){0.f, 0.f, 0.f, 0.f};

    #pragma unroll
    for (int kk = 0; kk < 6; ++kk) {
        bf16x8 b0 = *reinterpret_cast<const bf16x8*>(
            &Ws[(wn * 32 + lq) * 200 + kk * 32 + g * 8]);
        bf16x8 b1 = *reinterpret_cast<const bf16x8*>(
            &Ws[(wn * 32 + 16 + lq) * 200 + kk * 32 + g * 8]);
        #pragma unroll
        for (int s = 0; s < 4; ++s) {
            bf16x8 a = *reinterpret_cast<const bf16x8*>(
                &Xs[(wm * 64 + s * 16 + lq) * 200 + kk * 32 + g * 8]);
            acc[s][0] = __builtin_amdgcn_mfma_f32_16x16x32_bf16(a, b0, acc[s][0], 0, 0, 0);
            acc[s][1] = __builtin_amdgcn_mfma_f32_16x16x32_bf16(a, b1, acc[s][1], 0, 0, 0);
        }
    }

    const float SCALE = 0.20412414523193154f;  // 24^-0.5
    #pragma unroll
    for (int s = 0; s < 4; ++s) {
        #pragma unroll
        for (int jr = 0; jr < 4; ++jr) {
            int m = bm + wm * 64 + s * 16 + g * 4 + jr;
            int bbi = m >> 8, n = m & 255;
            #pragma unroll
            for (int t = 0; t < 2; ++t) {
                int c = bn + wn * 32 + t * 16 + lq;
                int t3 = c / 192;
                int rem = c - t3 * 192;
                int hh = rem / 24;
                int d = rem - hh * 24;
                size_t bh = (size_t)(bbi * HH + hh);
                float v = acc[s][t][jr];
                if (t3 == 0)      qb[(bh * NN + n) * HD2 + d] = f2bf(v * SCALE);
                else if (t3 == 1) kb[(bh * NN + n) * HD2 + d] = f2bf(v);
                else              vt[(bh * HD2 + d) * NN + n] = f2bf(v);
            }
        }
    }
}

// ---------------------------------------------------------------------------
// Kernel 2: MFMA attention. 1 block per (b,h), 8 waves x 32 q-rows.
// S^T = mfma(K, Q); bias+softmax in-register; out^T = mfma(V^T, P) with
// per-wave LDS bounce of P. Epilogue writes bf16 ab (B,N,C).
// ---------------------------------------------------------------------------
#define KSTR 40    // K LDS row stride (ushorts)
#define VSTR 272   // Vt LDS row stride
#define PSTR 80    // P LDS row stride

__global__ __launch_bounds__(512) void attn_mfma_kernel(
    const unsigned short* __restrict__ qb, const unsigned short* __restrict__ kb,
    const unsigned short* __restrict__ vt,
    const float* __restrict__ rel, const float* __restrict__ maskp,
    unsigned short* __restrict__ ab)
{
    __shared__ __align__(16) unsigned short Kl[NN * KSTR];
    __shared__ __align__(16) unsigned short Vl[HD2 * VSTR];
    __shared__ __align__(16) unsigned short Pw[8][32 * PSTR];

    const int tid = threadIdx.x;
    const int w  = tid >> 6;
    const int l  = tid & 63;
    const int lq = l & 15;
    const int g  = l >> 4;
    const int bid = blockIdx.x;
    const int h = bid & 7, b = bid >> 3;
    const int wi = b & (NWIN - 1);

    const unsigned short* kp = kb + (size_t)(b * HH + h) * NN * HD2;
    const unsigned short* vp = vt + (size_t)(b * HH + h) * HD2 * NN;
    const unsigned short* qp = qb + (size_t)(b * HH + h) * NN * HD2;

    for (int i = tid; i < 1024; i += 512) {
        int r = i >> 2, c = i & 3;
        *reinterpret_cast<uint4*>(&Kl[r * KSTR + c * 8]) =
            *reinterpret_cast<const uint4*>(kp + r * HD2 + c * 8);
    }
    for (int i = tid; i < 1024; i += 512) {
        int r = i >> 5, c = i & 31;
        *reinterpret_cast<uint4*>(&Vl[r * VSTR + c * 8]) =
            *reinterpret_cast<const uint4*>(vp + r * NN + c * 8);
    }

    bf16x8 qf[2];
    #pragma unroll
    for (int t = 0; t < 2; ++t)
        qf[t] = *reinterpret_cast<const bf16x8*>(
            qp + (w * 32 + t * 16 + lq) * HD2 + g * 8);

    __syncthreads();

    f32x4 acc[2][16];
    #pragma unroll
    for (int t = 0; t < 2; ++t)
        #pragma unroll
        for (int f = 0; f < 16; ++f)
            acc[t][f] = (f32x4){0.f, 0.f, 0.f, 0.f};

    #pragma unroll
    for (int f = 0; f < 16; ++f) {
        bf16x8 kf = *reinterpret_cast<const bf16x8*>(&Kl[(f * 16 + lq) * KSTR + g * 8]);
        acc[0][f] = __builtin_amdgcn_mfma_f32_16x16x32_bf16(kf, qf[0], acc[0][f], 0, 0, 0);
        acc[1][f] = __builtin_amdgcn_mfma_f32_16x16x32_bf16(kf, qf[1], acc[1][f], 0, 0, 0);
    }

    #pragma unroll
    for (int t = 0; t < 2; ++t) {
        int q = w * 32 + t * 16 + lq;
        const float* rp = rel + ((size_t)h * NN + q) * NN;
        const float* mp = maskp + ((size_t)wi * NN + q) * NN;
        #pragma unroll
        for (int f = 0; f < 16; ++f) {
            int k0 = f * 16 + g * 4;
            float4 rv = *reinterpret_cast<const float4*>(rp + k0);
            float4 mv = *reinterpret_cast<const float4*>(mp + k0);
            acc[t][f][0] += rv.x + mv.x;
            acc[t][f][1] += rv.y + mv.y;
            acc[t][f][2] += rv.z + mv.z;
            acc[t][f][3] += rv.w + mv.w;
        }
    }

    float inv[2];
    #pragma unroll
    for (int t = 0; t < 2; ++t) {
        float m = -3.0e38f;
        #pragma unroll
        for (int f = 0; f < 16; ++f)
            #pragma unroll
            for (int jr = 0; jr < 4; ++jr)
                m = fmaxf(m, acc[t][f][jr]);
        m = fmaxf(m, __shfl_xor(m, 16));
        m = fmaxf(m, __shfl_xor(m, 32));
        float s = 0.f;
        #pragma unroll
        for (int f = 0; f < 16; ++f)
            #pragma unroll
            for (int jr = 0; jr < 4; ++jr) {
                float e = __expf(acc[t][f][jr] - m);
                acc[t][f][jr] = e;
                s += e;
            }
        s += __shfl_xor(s, 16);
        s += __shfl_xor(s, 32);
        inv[t] = 1.0f / s;
    }

    f32x4 oacc[2][2];
    #pragma unroll
    for (int dt = 0; dt < 2; ++dt)
        #pragma unroll
        for (int t = 0; t < 2; ++t)
            oacc[dt][t] = (f32x4){0.f, 0.f, 0.f, 0.f};

    for (int c = 0; c < 4; ++c) {
        #pragma unroll
        for (int t = 0; t < 2; ++t)
            #pragma unroll
            for (int fp = 0; fp < 4; ++fp) {
                int f = c * 4 + fp;
                uint2 pk;
                pk.x = (unsigned int)f2bf(acc[t][f][0]) |
                       ((unsigned int)f2bf(acc[t][f][1]) << 16);
                pk.y = (unsigned int)f2bf(acc[t][f][2]) |
                       ((unsigned int)f2bf(acc[t][f][3]) << 16);
                *reinterpret_cast<uint2*>(
                    &Pw[w][(t * 16 + lq) * PSTR + fp * 16 + g * 4]) = pk;
            }
        __asm__ volatile("s_waitcnt lgkmcnt(0)" ::: "memory");
        #pragma unroll
        for (int k2 = 0; k2 < 2; ++k2) {
            bf16x8 bp0 = *reinterpret_cast<const bf16x8*>(
                &Pw[w][(0 * 16 + lq) * PSTR + k2 * 32 + g * 8]);
            bf16x8 bp1 = *reinterpret_cast<const bf16x8*>(
                &Pw[w][(1 * 16 + lq) * PSTR + k2 * 32 + g * 8]);
            #pragma unroll
            for (int dt = 0; dt < 2; ++dt) {
                bf16x8 av = *reinterpret_cast<const bf16x8*>(
                    &Vl[(dt * 16 + lq) * VSTR + c * 64 + k2 * 32 + g * 8]);
                oacc[dt][0] = __builtin_amdgcn_mfma_f32_16x16x32_bf16(av, bp0, oacc[dt][0], 0, 0, 0);
                oacc[dt][1] = __builtin_amdgcn_mfma_f32_16x16x32_bf16(av, bp1, oacc[dt][1], 0, 0, 0);
            }
        }
    }

    // epilogue: bf16 ab[(b,q)][h*24+d]
    #pragma unroll
    for (int t = 0; t < 2; ++t) {
        int qg = b * NN + w * 32 + t * 16 + lq;
        unsigned short* op = ab + (size_t)qg * CC + h * HD;
        #pragma unroll
        for (int dt = 0; dt < 2; ++dt) {
            int d0 = dt * 16 + g * 4;
            if (d0 < HD) {
                uint2 pk;
                pk.x = (unsigned int)f2bf(oacc[dt][t][0] * inv[t]) |
                       ((unsigned int)f2bf(oacc[dt][t][1] * inv[t]) << 16);
                pk.y = (unsigned int)f2bf(oacc[dt][t][2] * inv[t]) |
                       ((unsigned int)f2bf(oacc[dt][t][3] * inv[t]) << 16);
                *reinterpret_cast<uint2*>(op + d0) = pk;
            }
        }
    }
}

// ---------------------------------------------------------------------------
// Kernel 3: out = ab(bf16) @ wp^T + proj_b (bf16 MFMA, fp32 out)
// ---------------------------------------------------------------------------
__global__ __launch_bounds__(256) void proj_mfma_kernel(
    const unsigned short* __restrict__ ap, const unsigned short* __restrict__ wpb,
    const float* __restrict__ bias, float* __restrict__ out)
{
    __shared__ __align__(16) unsigned short Xs[128 * 200];
    __shared__ __align__(16) unsigned short Ws[64 * 200];

    const int tid = threadIdx.x;
    const int bm = blockIdx.x * 128, bn = blockIdx.y * 64;

    {
        const unsigned short* src = ap + (size_t)(bm + (tid >> 1)) * 192 + (tid & 1) * 96;
        unsigned short* dst = &Xs[(tid >> 1) * 200 + (tid & 1) * 96];
        #pragma unroll
        for (int i = 0; i < 12; ++i)
            *reinterpret_cast<uint4*>(dst + i * 8) =
                *reinterpret_cast<const uint4*>(src + i * 8);
    }
    {
        const unsigned short* src = wpb + (size_t)(bn + (tid >> 2)) * 192 + (tid & 3) * 48;
        unsigned short* dst = &Ws[(tid >> 2) * 200 + (tid & 3) * 48];
        #pragma unroll
        for (int i = 0; i < 6; ++i)
            *reinterpret_cast<uint4*>(dst + i * 8) =
                *reinterpret_cast<const uint4*>(src + i * 8);
    }
    __syncthreads();

    const int w = tid >> 6, l = tid & 63, lq = l & 15, g = l >> 4;
    const int wm = w >> 1, wn = w & 1;

    f32x4 acc[4][2];
    #pragma unroll
    for (int s = 0; s < 4; ++s)
        #pragma unroll
        for (int t = 0; t < 2; ++t)
            acc[s][t] = (f32x4){0.f, 0.f, 0.f, 0.f};

    #pragma unroll
    for (int kk = 0; kk < 6; ++kk) {
        bf16x8 b0 = *reinterpret_cast<const bf16x8*>(
            &Ws[(wn * 32 + lq) * 200 + kk * 32 + g * 8]);
        bf16x8 b1 = *reinterpret_cast<const bf16x8*>(
            &Ws[(wn * 32 + 16 + lq) * 200 + kk * 32 + g * 8]);
        #pragma unroll
        for (int s = 0; s < 4; ++s) {
            bf16x8 a = *reinterpret_cast<const bf16x8*>(
                &Xs[(wm * 64 + s * 16 + lq) * 200 + kk * 32 + g * 8]);
            acc[s][0] = __builtin_amdgcn_mfma_f32_16x16x32_bf16(a, b0, acc[s][0], 0, 0, 0);
            acc[s][1] = __builtin_amdgcn_mfma_f32_16x16x32_bf16(a, b1, acc[s][1], 0, 0, 0);
        }
    }

    #pragma unroll
    for (int s = 0; s < 4; ++s) {
        #pragma unroll
        for (int jr = 0; jr < 4; ++jr) {
            int m = bm + wm * 64 + s * 16 + g * 4 + jr;
            #pragma unroll
            for (int t = 0; t < 2; ++t) {
                int c = bn + wn * 32 + t * 16 + lq;
                out[(size_t)m * 192 + c] = acc[s][t][jr] + bias[c];
            }
        }
    }
}

extern "C" void kernel_launch(void* const* d_in, const int* in_sizes, int n_in,
                              void* d_out, int out_size, void* d_ws, size_t ws_size,
                              hipStream_t stream) {
    const float* x      = (const float*)d_in[0];
    const float* rel    = (const float*)d_in[1];
    const float* maskp  = (const float*)d_in[2];
    const float* qkv_w  = (const float*)d_in[3];
    const float* proj_w = (const float*)d_in[4];
    const float* proj_b = (const float*)d_in[5];
    float* out = (float*)d_out;

    unsigned char* wsb = (unsigned char*)d_ws;
    unsigned short* xbp = (unsigned short*)(wsb);                       // 12,582,912
    unsigned short* qbp = (unsigned short*)(wsb + XB_BYTES);            // 16,777,216
    unsigned short* kbp = (unsigned short*)(wsb + XB_BYTES + QB_BYTES);
    unsigned short* vtp = (unsigned short*)(wsb + XB_BYTES + 2 * QB_BYTES);
    unsigned short* abp = (unsigned short*)(wsb + XB_BYTES + 3 * QB_BYTES);
    unsigned short* wqb = (unsigned short*)(wsb + XB_BYTES + 3 * QB_BYTES + AB_BYTES);
    unsigned short* wpb = (unsigned short*)(wsb + XB_BYTES + 3 * QB_BYTES + AB_BYTES + WQ_BYTES);

    // zero Q pads (d=24..31) so padded-K garbage contributes 0 to S
    hipMemsetAsync(qbp, 0, QB_BYTES, stream);

    convert_kernel<<<6288, 256, 0, stream>>>(x, qkv_w, proj_w, xbp, wqb, wpb);
    qkv_mfma_kernel<<<dim3(256, 9), 256, 0, stream>>>(xbp, wqb, qbp, kbp, vtp);
    attn_mfma_kernel<<<dim3(BB * HH), 512, 0, stream>>>(qbp, kbp, vtp, rel, maskp, abp);
    proj_mfma_kernel<<<dim3(256, 3), 256, 0, stream>>>(abp, wpb, proj_b, out);
}

// Round 4
// 125.404 us; speedup vs baseline: 4.0682x; 1.1797x over previous
//
#include <hip/hip_runtime.h>
#include <hip/hip_bf16.h>

#define BB 128
#define NN 256
#define CC 192
#define HH 8
#define HD 24
#define HD2 32
#define NWIN 16

typedef __bf16 bf16x8 __attribute__((ext_vector_type(8)));
typedef float f32x4 __attribute__((ext_vector_type(4)));

#define QB_BYTES (size_t)(BB * HH * NN * HD2 * 2)   // 16,777,216
#define XB_BYTES (size_t)(BB * NN * CC * 2)         // 12,582,912
#define AB_BYTES (size_t)(BB * NN * CC * 2)         // 12,582,912
#define WQ_BYTES (size_t)(3 * CC * CC * 2)          // 221,184
#define WP_BYTES (size_t)(CC * CC * 2)              // 73,728
#define BIAS_BYTES (size_t)(128 * NN * NN * 2)      // 16,777,216

__device__ inline unsigned short f2bf(float x) {
    unsigned int u = __float_as_uint(x);
    unsigned int r = (u + 0x7FFFu + ((u >> 16) & 1u)) >> 16;
    return (unsigned short)r;
}

// ---------------------------------------------------------------------------
// Kernel 0a: fp32 -> bf16 conversion of x, qkv_w, proj_w (one pass)
// ---------------------------------------------------------------------------
#define NX4  1572864   // 6291456/4
#define NWQ4 27648     // 110592/4
#define NWP4 9216      // 36864/4

__global__ __launch_bounds__(256) void convert_kernel(
    const float* __restrict__ x, const float* __restrict__ wq,
    const float* __restrict__ wp,
    unsigned short* __restrict__ xb, unsigned short* __restrict__ wqb,
    unsigned short* __restrict__ wpb)
{
    int i = blockIdx.x * 256 + threadIdx.x;
    const float* src; unsigned short* dst; int j;
    if (i < NX4)              { src = x;  dst = xb;  j = i; }
    else if (i < NX4 + NWQ4)  { src = wq; dst = wqb; j = i - NX4; }
    else                      { src = wp; dst = wpb; j = i - NX4 - NWQ4; }
    float4 v = reinterpret_cast<const float4*>(src)[j];
    ushort4 o;
    o.x = f2bf(v.x); o.y = f2bf(v.y); o.z = f2bf(v.z); o.w = f2bf(v.w);
    reinterpret_cast<ushort4*>(dst)[j] = o;
}

// ---------------------------------------------------------------------------
// Kernel 0b: combined bias bias16[c][q][k] = bf16(rel[c>>4] + mask[c&15])
// 128 combos x 64K elems; fully coalesced read & write.
// ---------------------------------------------------------------------------
__global__ __launch_bounds__(256) void bias_kernel(
    const float* __restrict__ rel, const float* __restrict__ maskp,
    unsigned short* __restrict__ bias16)
{
    int idx = blockIdx.x * 256 + threadIdx.x;     // ushort4 units, 2,097,152 total
    int c = idx >> 14;                            // 16384 ushort4 per combo
    int rem = idx & 16383;
    int q = rem >> 6;
    int k4 = rem & 63;
    int h = c >> 4, wi = c & 15;
    float4 rv = *reinterpret_cast<const float4*>(rel + ((size_t)h * NN + q) * NN + k4 * 4);
    float4 mv = *reinterpret_cast<const float4*>(maskp + ((size_t)wi * NN + q) * NN + k4 * 4);
    ushort4 o;
    o.x = f2bf(rv.x + mv.x); o.y = f2bf(rv.y + mv.y);
    o.z = f2bf(rv.z + mv.z); o.w = f2bf(rv.w + mv.w);
    *reinterpret_cast<ushort4*>(bias16 + ((size_t)c << 16) + q * NN + k4 * 4) = o;
}

// ---------------------------------------------------------------------------
// Kernel 1: qkv = xb @ wq^T (bf16 MFMA, full K=192 in LDS, 128x64 tile)
// XCD-swizzled 1D grid: each XCD keeps a 1.5MB X chunk L2-resident across bn.
// ---------------------------------------------------------------------------
__global__ __launch_bounds__(256) void qkv_mfma_kernel(
    const unsigned short* __restrict__ xb, const unsigned short* __restrict__ wqb,
    unsigned short* __restrict__ qb, unsigned short* __restrict__ kb,
    unsigned short* __restrict__ vt)
{
    __shared__ __align__(16) unsigned short Xs[128 * 200];
    __shared__ __align__(16) unsigned short Ws[64 * 200];

    const int tid = threadIdx.x;
    const int wgid = blockIdx.x;                  // 2304 = 8 XCD * 288
    const int xcd = wgid & 7;
    const int j = wgid >> 3;                      // 0..287
    const int bm = (xcd * 32 + (j & 31)) * 128;
    const int bn = (j >> 5) * 64;

    {
        const unsigned short* src = xb + (size_t)(bm + (tid >> 1)) * 192 + (tid & 1) * 96;
        unsigned short* dst = &Xs[(tid >> 1) * 200 + (tid & 1) * 96];
        #pragma unroll
        for (int i = 0; i < 12; ++i)
            *reinterpret_cast<uint4*>(dst + i * 8) =
                *reinterpret_cast<const uint4*>(src + i * 8);
    }
    {
        const unsigned short* src = wqb + (size_t)(bn + (tid >> 2)) * 192 + (tid & 3) * 48;
        unsigned short* dst = &Ws[(tid >> 2) * 200 + (tid & 3) * 48];
        #pragma unroll
        for (int i = 0; i < 6; ++i)
            *reinterpret_cast<uint4*>(dst + i * 8) =
                *reinterpret_cast<const uint4*>(src + i * 8);
    }
    __syncthreads();

    const int w = tid >> 6, l = tid & 63, lq = l & 15, g = l >> 4;
    const int wm = w >> 1, wn = w & 1;

    f32x4 acc[4][2];
    #pragma unroll
    for (int s = 0; s < 4; ++s)
        #pragma unroll
        for (int t = 0; t < 2; ++t)
            acc[s][t] = (f32x4){0.f, 0.f, 0.f, 0.f};

    #pragma unroll
    for (int kk = 0; kk < 6; ++kk) {
        bf16x8 b0 = *reinterpret_cast<const bf16x8*>(
            &Ws[(wn * 32 + lq) * 200 + kk * 32 + g * 8]);
        bf16x8 b1 = *reinterpret_cast<const bf16x8*>(
            &Ws[(wn * 32 + 16 + lq) * 200 + kk * 32 + g * 8]);
        #pragma unroll
        for (int s = 0; s < 4; ++s) {
            bf16x8 a = *reinterpret_cast<const bf16x8*>(
                &Xs[(wm * 64 + s * 16 + lq) * 200 + kk * 32 + g * 8]);
            acc[s][0] = __builtin_amdgcn_mfma_f32_16x16x32_bf16(a, b0, acc[s][0], 0, 0, 0);
            acc[s][1] = __builtin_amdgcn_mfma_f32_16x16x32_bf16(a, b1, acc[s][1], 0, 0, 0);
        }
    }

    const float SCALE = 0.20412414523193154f;  // 24^-0.5
    #pragma unroll
    for (int s = 0; s < 4; ++s) {
        #pragma unroll
        for (int jr = 0; jr < 4; ++jr) {
            int m = bm + wm * 64 + s * 16 + g * 4 + jr;
            int bbi = m >> 8, n = m & 255;
            #pragma unroll
            for (int t = 0; t < 2; ++t) {
                int c = bn + wn * 32 + t * 16 + lq;
                int t3 = c / 192;
                int rem = c - t3 * 192;
                int hh = rem / 24;
                int d = rem - hh * 24;
                size_t bh = (size_t)(bbi * HH + hh);
                float v = acc[s][t][jr];
                if (t3 == 0)      qb[(bh * NN + n) * HD2 + d] = f2bf(v * SCALE);
                else if (t3 == 1) kb[(bh * NN + n) * HD2 + d] = f2bf(v);
                else              vt[(bh * HD2 + d) * NN + n] = f2bf(v);
            }
        }
    }
}

// ---------------------------------------------------------------------------
// Kernel 2: MFMA attention. 1 block per (b,h); XCD-swizzled so the 8 blocks
// sharing bias combo c = h*16 + b%16 land on the same XCD (2MB L2-resident).
// ---------------------------------------------------------------------------
#define KSTR 40
#define VSTR 272
#define PSTR 80

__global__ __launch_bounds__(512) void attn_mfma_kernel(
    const unsigned short* __restrict__ qb, const unsigned short* __restrict__ kb,
    const unsigned short* __restrict__ vt,
    const unsigned short* __restrict__ bias16,
    unsigned short* __restrict__ ab)
{
    __shared__ __align__(16) unsigned short Kl[NN * KSTR];
    __shared__ __align__(16) unsigned short Vl[HD2 * VSTR];
    __shared__ __align__(16) unsigned short Pw[8][32 * PSTR];

    const int tid = threadIdx.x;
    const int w  = tid >> 6;
    const int l  = tid & 63;
    const int lq = l & 15;
    const int g  = l >> 4;
    // swizzle: wgid = j*128 + c  ->  c = combo (h*16+wi), j = which batch-copy
    const int wgid = blockIdx.x;
    const int c = wgid & 127;
    const int j = wgid >> 7;
    const int h = c >> 4;
    const int b = (c & 15) + (j << 4);

    const unsigned short* kp = kb + (size_t)(b * HH + h) * NN * HD2;
    const unsigned short* vp = vt + (size_t)(b * HH + h) * HD2 * NN;
    const unsigned short* qp = qb + (size_t)(b * HH + h) * NN * HD2;
    const unsigned short* bp = bias16 + ((size_t)c << 16);

    for (int i = tid; i < 1024; i += 512) {
        int r = i >> 2, cc = i & 3;
        *reinterpret_cast<uint4*>(&Kl[r * KSTR + cc * 8]) =
            *reinterpret_cast<const uint4*>(kp + r * HD2 + cc * 8);
    }
    for (int i = tid; i < 1024; i += 512) {
        int r = i >> 5, cc = i & 31;
        *reinterpret_cast<uint4*>(&Vl[r * VSTR + cc * 8]) =
            *reinterpret_cast<const uint4*>(vp + r * NN + cc * 8);
    }

    bf16x8 qf[2];
    #pragma unroll
    for (int t = 0; t < 2; ++t)
        qf[t] = *reinterpret_cast<const bf16x8*>(
            qp + (w * 32 + t * 16 + lq) * HD2 + g * 8);

    __syncthreads();

    f32x4 acc[2][16];
    #pragma unroll
    for (int t = 0; t < 2; ++t)
        #pragma unroll
        for (int f = 0; f < 16; ++f)
            acc[t][f] = (f32x4){0.f, 0.f, 0.f, 0.f};

    #pragma unroll
    for (int f = 0; f < 16; ++f) {
        bf16x8 kf = *reinterpret_cast<const bf16x8*>(&Kl[(f * 16 + lq) * KSTR + g * 8]);
        acc[0][f] = __builtin_amdgcn_mfma_f32_16x16x32_bf16(kf, qf[0], acc[0][f], 0, 0, 0);
        acc[1][f] = __builtin_amdgcn_mfma_f32_16x16x32_bf16(kf, qf[1], acc[1][f], 0, 0, 0);
    }

    // bias add: bf16 combined bias, uint2 (4 vals) per (t,f); L2-resident
    #pragma unroll
    for (int t = 0; t < 2; ++t) {
        int q = w * 32 + t * 16 + lq;
        const unsigned short* bq = bp + (size_t)q * NN;
        #pragma unroll
        for (int f = 0; f < 16; ++f) {
            uint2 bv = *reinterpret_cast<const uint2*>(bq + f * 16 + g * 4);
            acc[t][f][0] += __uint_as_float(bv.x << 16);
            acc[t][f][1] += __uint_as_float(bv.x & 0xffff0000u);
            acc[t][f][2] += __uint_as_float(bv.y << 16);
            acc[t][f][3] += __uint_as_float(bv.y & 0xffff0000u);
        }
    }

    float inv[2];
    #pragma unroll
    for (int t = 0; t < 2; ++t) {
        float m = -3.0e38f;
        #pragma unroll
        for (int f = 0; f < 16; ++f)
            #pragma unroll
            for (int jr = 0; jr < 4; ++jr)
                m = fmaxf(m, acc[t][f][jr]);
        m = fmaxf(m, __shfl_xor(m, 16));
        m = fmaxf(m, __shfl_xor(m, 32));
        float s = 0.f;
        #pragma unroll
        for (int f = 0; f < 16; ++f)
            #pragma unroll
            for (int jr = 0; jr < 4; ++jr) {
                float e = __expf(acc[t][f][jr] - m);
                acc[t][f][jr] = e;
                s += e;
            }
        s += __shfl_xor(s, 16);
        s += __shfl_xor(s, 32);
        inv[t] = 1.0f / s;
    }

    f32x4 oacc[2][2];
    #pragma unroll
    for (int dt = 0; dt < 2; ++dt)
        #pragma unroll
        for (int t = 0; t < 2; ++t)
            oacc[dt][t] = (f32x4){0.f, 0.f, 0.f, 0.f};

    for (int cc = 0; cc < 4; ++cc) {
        #pragma unroll
        for (int t = 0; t < 2; ++t)
            #pragma unroll
            for (int fp = 0; fp < 4; ++fp) {
                int f = cc * 4 + fp;
                uint2 pk;
                pk.x = (unsigned int)f2bf(acc[t][f][0]) |
                       ((unsigned int)f2bf(acc[t][f][1]) << 16);
                pk.y = (unsigned int)f2bf(acc[t][f][2]) |
                       ((unsigned int)f2bf(acc[t][f][3]) << 16);
                *reinterpret_cast<uint2*>(
                    &Pw[w][(t * 16 + lq) * PSTR + fp * 16 + g * 4]) = pk;
            }
        __asm__ volatile("s_waitcnt lgkmcnt(0)" ::: "memory");
        #pragma unroll
        for (int k2 = 0; k2 < 2; ++k2) {
            bf16x8 bp0 = *reinterpret_cast<const bf16x8*>(
                &Pw[w][(0 * 16 + lq) * PSTR + k2 * 32 + g * 8]);
            bf16x8 bp1 = *reinterpret_cast<const bf16x8*>(
                &Pw[w][(1 * 16 + lq) * PSTR + k2 * 32 + g * 8]);
            #pragma unroll
            for (int dt = 0; dt < 2; ++dt) {
                bf16x8 av = *reinterpret_cast<const bf16x8*>(
                    &Vl[(dt * 16 + lq) * VSTR + cc * 64 + k2 * 32 + g * 8]);
                oacc[dt][0] = __builtin_amdgcn_mfma_f32_16x16x32_bf16(av, bp0, oacc[dt][0], 0, 0, 0);
                oacc[dt][1] = __builtin_amdgcn_mfma_f32_16x16x32_bf16(av, bp1, oacc[dt][1], 0, 0, 0);
            }
        }
    }

    #pragma unroll
    for (int t = 0; t < 2; ++t) {
        int qg = b * NN + w * 32 + t * 16 + lq;
        unsigned short* op = ab + (size_t)qg * CC + h * HD;
        #pragma unroll
        for (int dt = 0; dt < 2; ++dt) {
            int d0 = dt * 16 + g * 4;
            if (d0 < HD) {
                uint2 pk;
                pk.x = (unsigned int)f2bf(oacc[dt][t][0] * inv[t]) |
                       ((unsigned int)f2bf(oacc[dt][t][1] * inv[t]) << 16);
                pk.y = (unsigned int)f2bf(oacc[dt][t][2] * inv[t]) |
                       ((unsigned int)f2bf(oacc[dt][t][3] * inv[t]) << 16);
                *reinterpret_cast<uint2*>(op + d0) = pk;
            }
        }
    }
}

// ---------------------------------------------------------------------------
// Kernel 3: out = ab(bf16) @ wp^T + proj_b (bf16 MFMA, fp32 out), XCD-swizzled
// ---------------------------------------------------------------------------
__global__ __launch_bounds__(256) void proj_mfma_kernel(
    const unsigned short* __restrict__ ap, const unsigned short* __restrict__ wpb,
    const float* __restrict__ bias, float* __restrict__ out)
{
    __shared__ __align__(16) unsigned short Xs[128 * 200];
    __shared__ __align__(16) unsigned short Ws[64 * 200];

    const int tid = threadIdx.x;
    const int wgid = blockIdx.x;                  // 768 = 8 XCD * 96
    const int xcd = wgid & 7;
    const int j = wgid >> 3;                      // 0..95
    const int bm = (xcd * 32 + (j & 31)) * 128;
    const int bn = (j >> 5) * 64;

    {
        const unsigned short* src = ap + (size_t)(bm + (tid >> 1)) * 192 + (tid & 1) * 96;
        unsigned short* dst = &Xs[(tid >> 1) * 200 + (tid & 1) * 96];
        #pragma unroll
        for (int i = 0; i < 12; ++i)
            *reinterpret_cast<uint4*>(dst + i * 8) =
                *reinterpret_cast<const uint4*>(src + i * 8);
    }
    {
        const unsigned short* src = wpb + (size_t)(bn + (tid >> 2)) * 192 + (tid & 3) * 48;
        unsigned short* dst = &Ws[(tid >> 2) * 200 + (tid & 3) * 48];
        #pragma unroll
        for (int i = 0; i < 6; ++i)
            *reinterpret_cast<uint4*>(dst + i * 8) =
                *reinterpret_cast<const uint4*>(src + i * 8);
    }
    __syncthreads();

    const int w = tid >> 6, l = tid & 63, lq = l & 15, g = l >> 4;
    const int wm = w >> 1, wn = w & 1;

    f32x4 acc[4][2];
    #pragma unroll
    for (int s = 0; s < 4; ++s)
        #pragma unroll
        for (int t = 0; t < 2; ++t)
            acc[s][t] = (f32x4){0.f, 0.f, 0.f, 0.f};

    #pragma unroll
    for (int kk = 0; kk < 6; ++kk) {
        bf16x8 b0 = *reinterpret_cast<const bf16x8*>(
            &Ws[(wn * 32 + lq) * 200 + kk * 32 + g * 8]);
        bf16x8 b1 = *reinterpret_cast<const bf16x8*>(
            &Ws[(wn * 32 + 16 + lq) * 200 + kk * 32 + g * 8]);
        #pragma unroll
        for (int s = 0; s < 4; ++s) {
            bf16x8 a = *reinterpret_cast<const bf16x8*>(
                &Xs[(wm * 64 + s * 16 + lq) * 200 + kk * 32 + g * 8]);
            acc[s][0] = __builtin_amdgcn_mfma_f32_16x16x32_bf16(a, b0, acc[s][0], 0, 0, 0);
            acc[s][1] = __builtin_amdgcn_mfma_f32_16x16x32_bf16(a, b1, acc[s][1], 0, 0, 0);
        }
    }

    #pragma unroll
    for (int s = 0; s < 4; ++s) {
        #pragma unroll
        for (int jr = 0; jr < 4; ++jr) {
            int m = bm + wm * 64 + s * 16 + g * 4 + jr;
            #pragma unroll
            for (int t = 0; t < 2; ++t) {
                int c = bn + wn * 32 + t * 16 + lq;
                out[(size_t)m * 192 + c] = acc[s][t][jr] + bias[c];
            }
        }
    }
}

extern "C" void kernel_launch(void* const* d_in, const int* in_sizes, int n_in,
                              void* d_out, int out_size, void* d_ws, size_t ws_size,
                              hipStream_t stream) {
    const float* x      = (const float*)d_in[0];
    const float* rel    = (const float*)d_in[1];
    const float* maskp  = (const float*)d_in[2];
    const float* qkv_w  = (const float*)d_in[3];
    const float* proj_w = (const float*)d_in[4];
    const float* proj_b = (const float*)d_in[5];
    float* out = (float*)d_out;

    unsigned char* wsb = (unsigned char*)d_ws;
    size_t off = 0;
    unsigned short* xbp  = (unsigned short*)(wsb + off); off += XB_BYTES;
    unsigned short* qbp  = (unsigned short*)(wsb + off); off += QB_BYTES;
    unsigned short* kbp  = (unsigned short*)(wsb + off); off += QB_BYTES;
    unsigned short* vtp  = (unsigned short*)(wsb + off); off += QB_BYTES;
    unsigned short* abp  = (unsigned short*)(wsb + off); off += AB_BYTES;
    unsigned short* wqb  = (unsigned short*)(wsb + off); off += WQ_BYTES;
    unsigned short* wpb  = (unsigned short*)(wsb + off); off += WP_BYTES;
    unsigned short* bias16 = (unsigned short*)(wsb + off); off += BIAS_BYTES;

    // zero Q pads (d=24..31) so padded-K garbage contributes 0 to S
    hipMemsetAsync(qbp, 0, QB_BYTES, stream);

    bias_kernel<<<8192, 256, 0, stream>>>(rel, maskp, bias16);
    convert_kernel<<<6288, 256, 0, stream>>>(x, qkv_w, proj_w, xbp, wqb, wpb);
    qkv_mfma_kernel<<<2304, 256, 0, stream>>>(xbp, wqb, qbp, kbp, vtp);
    attn_mfma_kernel<<<1024, 512, 0, stream>>>(qbp, kbp, vtp, bias16, abp);
    proj_mfma_kernel<<<768, 256, 0, stream>>>(abp, wpb, proj_b, out);
}

// Round 5
// 112.963 us; speedup vs baseline: 4.5162x; 1.1101x over previous
//
#include <hip/hip_runtime.h>
#include <hip/hip_bf16.h>

#define BB 128
#define NN 256
#define CC 192
#define HH 8
#define HD 24
#define HD2 32
#define NWIN 16

typedef __bf16 bf16x8 __attribute__((ext_vector_type(8)));
typedef float f32x4 __attribute__((ext_vector_type(4)));

#define QB_BYTES (size_t)(BB * HH * NN * HD2 * 2)   // 16,777,216
#define XB_BYTES (size_t)(BB * NN * CC * 2)         // 12,582,912
#define AB_BYTES (size_t)(BB * NN * CC * 2)         // 12,582,912
#define WQ_BYTES (size_t)(3 * CC * CC * 2)          // 221,184
#define WP_BYTES (size_t)(CC * CC * 2)              // 73,728
#define BIAS_BYTES (size_t)(128 * NN * NN * 2)      // 16,777,216

// hardware bf16 converts (v_cvt_pk_bf16_f32 / scalar cvt)
__device__ inline unsigned int pkbf(float a, float b) {
    __hip_bfloat162 h = __float22bfloat162_rn(float2{a, b});
    return *reinterpret_cast<unsigned int*>(&h);
}
__device__ inline unsigned short sbf(float a) {
    __hip_bfloat16 h = __float2bfloat16(a);
    return *reinterpret_cast<unsigned short*>(&h);
}

// ---------------------------------------------------------------------------
// Kernel 0a: fp32 -> bf16 conversion of x, qkv_w, proj_w (one pass)
// ---------------------------------------------------------------------------
#define NX4  1572864   // 6291456/4
#define NWQ4 27648     // 110592/4
#define NWP4 9216      // 36864/4

__global__ __launch_bounds__(256) void convert_kernel(
    const float* __restrict__ x, const float* __restrict__ wq,
    const float* __restrict__ wp,
    unsigned short* __restrict__ xb, unsigned short* __restrict__ wqb,
    unsigned short* __restrict__ wpb)
{
    int i = blockIdx.x * 256 + threadIdx.x;
    const float* src; unsigned short* dst; int j;
    if (i < NX4)              { src = x;  dst = xb;  j = i; }
    else if (i < NX4 + NWQ4)  { src = wq; dst = wqb; j = i - NX4; }
    else                      { src = wp; dst = wpb; j = i - NX4 - NWQ4; }
    float4 v = reinterpret_cast<const float4*>(src)[j];
    uint2 o;
    o.x = pkbf(v.x, v.y);
    o.y = pkbf(v.z, v.w);
    reinterpret_cast<uint2*>(dst)[j] = o;
}

// ---------------------------------------------------------------------------
// Kernel 0b: combined bias bias16[c][q][k] = bf16(rel[c>>4] + mask[c&15])
// ---------------------------------------------------------------------------
__global__ __launch_bounds__(256) void bias_kernel(
    const float* __restrict__ rel, const float* __restrict__ maskp,
    unsigned short* __restrict__ bias16)
{
    int idx = blockIdx.x * 256 + threadIdx.x;     // ushort4 units
    int c = idx >> 14;
    int rem = idx & 16383;
    int q = rem >> 6;
    int k4 = rem & 63;
    int h = c >> 4, wi = c & 15;
    float4 rv = *reinterpret_cast<const float4*>(rel + ((size_t)h * NN + q) * NN + k4 * 4);
    float4 mv = *reinterpret_cast<const float4*>(maskp + ((size_t)wi * NN + q) * NN + k4 * 4);
    uint2 o;
    o.x = pkbf(rv.x + mv.x, rv.y + mv.y);
    o.y = pkbf(rv.z + mv.z, rv.w + mv.w);
    *reinterpret_cast<uint2*>(bias16 + ((size_t)c << 16) + q * NN + k4 * 4) = o;
}

// ---------------------------------------------------------------------------
// Kernel 1: qkv = xb @ wq^T (bf16 MFMA, full K=192 in LDS, 128x64 tile)
// ---------------------------------------------------------------------------
__global__ __launch_bounds__(256) void qkv_mfma_kernel(
    const unsigned short* __restrict__ xb, const unsigned short* __restrict__ wqb,
    unsigned short* __restrict__ qb, unsigned short* __restrict__ kb,
    unsigned short* __restrict__ vt)
{
    __shared__ __align__(16) unsigned short Xs[128 * 200];
    __shared__ __align__(16) unsigned short Ws[64 * 200];

    const int tid = threadIdx.x;
    const int wgid = blockIdx.x;                  // 2304 = 8 XCD * 288
    const int xcd = wgid & 7;
    const int j = wgid >> 3;
    const int bm = (xcd * 32 + (j & 31)) * 128;
    const int bn = (j >> 5) * 64;

    {
        const unsigned short* src = xb + (size_t)(bm + (tid >> 1)) * 192 + (tid & 1) * 96;
        unsigned short* dst = &Xs[(tid >> 1) * 200 + (tid & 1) * 96];
        #pragma unroll
        for (int i = 0; i < 12; ++i)
            *reinterpret_cast<uint4*>(dst + i * 8) =
                *reinterpret_cast<const uint4*>(src + i * 8);
    }
    {
        const unsigned short* src = wqb + (size_t)(bn + (tid >> 2)) * 192 + (tid & 3) * 48;
        unsigned short* dst = &Ws[(tid >> 2) * 200 + (tid & 3) * 48];
        #pragma unroll
        for (int i = 0; i < 6; ++i)
            *reinterpret_cast<uint4*>(dst + i * 8) =
                *reinterpret_cast<const uint4*>(src + i * 8);
    }
    __syncthreads();

    const int w = tid >> 6, l = tid & 63, lq = l & 15, g = l >> 4;
    const int wm = w >> 1, wn = w & 1;

    f32x4 acc[4][2];
    #pragma unroll
    for (int s = 0; s < 4; ++s)
        #pragma unroll
        for (int t = 0; t < 2; ++t)
            acc[s][t] = (f32x4){0.f, 0.f, 0.f, 0.f};

    #pragma unroll
    for (int kk = 0; kk < 6; ++kk) {
        bf16x8 b0 = *reinterpret_cast<const bf16x8*>(
            &Ws[(wn * 32 + lq) * 200 + kk * 32 + g * 8]);
        bf16x8 b1 = *reinterpret_cast<const bf16x8*>(
            &Ws[(wn * 32 + 16 + lq) * 200 + kk * 32 + g * 8]);
        #pragma unroll
        for (int s = 0; s < 4; ++s) {
            bf16x8 a = *reinterpret_cast<const bf16x8*>(
                &Xs[(wm * 64 + s * 16 + lq) * 200 + kk * 32 + g * 8]);
            acc[s][0] = __builtin_amdgcn_mfma_f32_16x16x32_bf16(a, b0, acc[s][0], 0, 0, 0);
            acc[s][1] = __builtin_amdgcn_mfma_f32_16x16x32_bf16(a, b1, acc[s][1], 0, 0, 0);
        }
    }

    const float SCALE = 0.20412414523193154f;  // 24^-0.5
    #pragma unroll
    for (int s = 0; s < 4; ++s) {
        #pragma unroll
        for (int jr = 0; jr < 4; ++jr) {
            int m = bm + wm * 64 + s * 16 + g * 4 + jr;
            int bbi = m >> 8, n = m & 255;
            #pragma unroll
            for (int t = 0; t < 2; ++t) {
                int c = bn + wn * 32 + t * 16 + lq;
                int t3 = c / 192;
                int rem = c - t3 * 192;
                int hh = rem / 24;
                int d = rem - hh * 24;
                size_t bh = (size_t)(bbi * HH + hh);
                float v = acc[s][t][jr];
                if (t3 == 0)      qb[(bh * NN + n) * HD2 + d] = sbf(v * SCALE);
                else if (t3 == 1) kb[(bh * NN + n) * HD2 + d] = sbf(v);
                else              vt[(bh * HD2 + d) * NN + n] = sbf(v);
            }
        }
    }
}

// ---------------------------------------------------------------------------
// Kernel 2: flash-style MFMA attention. 1 block per (b,h), 8 waves x 32 q.
// k tiled in 4 x 64; online softmax; score acc shrinks 128->32 regs.
// ---------------------------------------------------------------------------
#define KSTR 40
#define VSTR 272
#define PSTR 72

__global__ __launch_bounds__(512) void attn_mfma_kernel(
    const unsigned short* __restrict__ qb, const unsigned short* __restrict__ kb,
    const unsigned short* __restrict__ vt,
    const unsigned short* __restrict__ bias16,
    unsigned short* __restrict__ ab)
{
    __shared__ __align__(16) unsigned short Kl[NN * KSTR];       // 20480 B
    __shared__ __align__(16) unsigned short Vl[HD2 * VSTR];      // 17408 B
    __shared__ __align__(16) unsigned short Pw[8][32 * PSTR];    // 36864 B

    const int tid = threadIdx.x;
    const int w  = tid >> 6;
    const int l  = tid & 63;
    const int lq = l & 15;
    const int g  = l >> 4;
    const int wgid = blockIdx.x;
    const int c = wgid & 127;          // bias combo = h*16 + wi (XCD-local)
    const int j = wgid >> 7;
    const int h = c >> 4;
    const int b = (c & 15) + (j << 4);

    const unsigned short* kp = kb + (size_t)(b * HH + h) * NN * HD2;
    const unsigned short* vp = vt + (size_t)(b * HH + h) * HD2 * NN;
    const unsigned short* qp = qb + (size_t)(b * HH + h) * NN * HD2;
    const unsigned short* bp = bias16 + ((size_t)c << 16);

    for (int i = tid; i < 1024; i += 512) {
        int r = i >> 2, cc = i & 3;
        *reinterpret_cast<uint4*>(&Kl[r * KSTR + cc * 8]) =
            *reinterpret_cast<const uint4*>(kp + r * HD2 + cc * 8);
    }
    for (int i = tid; i < 1024; i += 512) {
        int r = i >> 5, cc = i & 31;
        *reinterpret_cast<uint4*>(&Vl[r * VSTR + cc * 8]) =
            *reinterpret_cast<const uint4*>(vp + r * NN + cc * 8);
    }

    bf16x8 qf[2];
    #pragma unroll
    for (int t = 0; t < 2; ++t)
        qf[t] = *reinterpret_cast<const bf16x8*>(
            qp + (w * 32 + t * 16 + lq) * HD2 + g * 8);

    // bias row pointers per t
    const unsigned short* bq0 = bp + (size_t)(w * 32 + lq) * NN;
    const unsigned short* bq1 = bp + (size_t)(w * 32 + 16 + lq) * NN;

    __syncthreads();

    float m_run[2] = {-3.0e38f, -3.0e38f};
    float s_run[2] = {0.f, 0.f};
    f32x4 oacc[2][2];                  // [dt][t]
    #pragma unroll
    for (int dt = 0; dt < 2; ++dt)
        #pragma unroll
        for (int t = 0; t < 2; ++t)
            oacc[dt][t] = (f32x4){0.f, 0.f, 0.f, 0.f};

    for (int kt = 0; kt < 4; ++kt) {
        // ---- QK^T tile: acc[t][f][jr] = S[k = kt*64+16f+4g+jr][q=32w+16t+lq]
        f32x4 acc[2][4];
        #pragma unroll
        for (int t = 0; t < 2; ++t)
            #pragma unroll
            for (int f = 0; f < 4; ++f)
                acc[t][f] = (f32x4){0.f, 0.f, 0.f, 0.f};
        #pragma unroll
        for (int f = 0; f < 4; ++f) {
            bf16x8 kf = *reinterpret_cast<const bf16x8*>(
                &Kl[(kt * 64 + f * 16 + lq) * KSTR + g * 8]);
            acc[0][f] = __builtin_amdgcn_mfma_f32_16x16x32_bf16(kf, qf[0], acc[0][f], 0, 0, 0);
            acc[1][f] = __builtin_amdgcn_mfma_f32_16x16x32_bf16(kf, qf[1], acc[1][f], 0, 0, 0);
        }

        // ---- bias add (bf16 combined, L2-resident)
        #pragma unroll
        for (int t = 0; t < 2; ++t) {
            const unsigned short* bq = t ? bq1 : bq0;
            #pragma unroll
            for (int f = 0; f < 4; ++f) {
                uint2 bv = *reinterpret_cast<const uint2*>(bq + kt * 64 + f * 16 + g * 4);
                acc[t][f][0] += __uint_as_float(bv.x << 16);
                acc[t][f][1] += __uint_as_float(bv.x & 0xffff0000u);
                acc[t][f][2] += __uint_as_float(bv.y << 16);
                acc[t][f][3] += __uint_as_float(bv.y & 0xffff0000u);
            }
        }

        // ---- online softmax update (exact, fp32)
        #pragma unroll
        for (int t = 0; t < 2; ++t) {
            float tm = -3.0e38f;
            #pragma unroll
            for (int f = 0; f < 4; ++f)
                #pragma unroll
                for (int jr = 0; jr < 4; ++jr)
                    tm = fmaxf(tm, acc[t][f][jr]);
            tm = fmaxf(tm, __shfl_xor(tm, 16));
            tm = fmaxf(tm, __shfl_xor(tm, 32));
            float m_new = fmaxf(m_run[t], tm);
            float r = __expf(m_run[t] - m_new);
            float ssum = 0.f;
            #pragma unroll
            for (int f = 0; f < 4; ++f)
                #pragma unroll
                for (int jr = 0; jr < 4; ++jr) {
                    float e = __expf(acc[t][f][jr] - m_new);
                    acc[t][f][jr] = e;
                    ssum += e;
                }
            ssum += __shfl_xor(ssum, 16);
            ssum += __shfl_xor(ssum, 32);
            s_run[t] = s_run[t] * r + ssum;
            m_run[t] = m_new;
            #pragma unroll
            for (int dt = 0; dt < 2; ++dt) {
                oacc[dt][t][0] *= r; oacc[dt][t][1] *= r;
                oacc[dt][t][2] *= r; oacc[dt][t][3] *= r;
            }
        }

        // ---- P tile -> per-wave LDS bounce ([q][k] layout, bf16)
        #pragma unroll
        for (int t = 0; t < 2; ++t)
            #pragma unroll
            for (int f = 0; f < 4; ++f) {
                uint2 pk;
                pk.x = pkbf(acc[t][f][0], acc[t][f][1]);
                pk.y = pkbf(acc[t][f][2], acc[t][f][3]);
                *reinterpret_cast<uint2*>(
                    &Pw[w][(t * 16 + lq) * PSTR + f * 16 + g * 4]) = pk;
            }
        __asm__ volatile("s_waitcnt lgkmcnt(0)" ::: "memory");

        // ---- PV accumulate for this k tile
        #pragma unroll
        for (int k2 = 0; k2 < 2; ++k2) {
            bf16x8 bp0 = *reinterpret_cast<const bf16x8*>(
                &Pw[w][(0 * 16 + lq) * PSTR + k2 * 32 + g * 8]);
            bf16x8 bp1 = *reinterpret_cast<const bf16x8*>(
                &Pw[w][(1 * 16 + lq) * PSTR + k2 * 32 + g * 8]);
            #pragma unroll
            for (int dt = 0; dt < 2; ++dt) {
                bf16x8 av = *reinterpret_cast<const bf16x8*>(
                    &Vl[(dt * 16 + lq) * VSTR + kt * 64 + k2 * 32 + g * 8]);
                oacc[dt][0] = __builtin_amdgcn_mfma_f32_16x16x32_bf16(av, bp0, oacc[dt][0], 0, 0, 0);
                oacc[dt][1] = __builtin_amdgcn_mfma_f32_16x16x32_bf16(av, bp1, oacc[dt][1], 0, 0, 0);
            }
        }
    }

    // ---- epilogue: out[q][h*24+d] = oacc / s_run, bf16
    #pragma unroll
    for (int t = 0; t < 2; ++t) {
        float inv = 1.0f / s_run[t];
        int qg = b * NN + w * 32 + t * 16 + lq;
        unsigned short* op = ab + (size_t)qg * CC + h * HD;
        #pragma unroll
        for (int dt = 0; dt < 2; ++dt) {
            int d0 = dt * 16 + g * 4;
            if (d0 < HD) {
                uint2 pk;
                pk.x = pkbf(oacc[dt][t][0] * inv, oacc[dt][t][1] * inv);
                pk.y = pkbf(oacc[dt][t][2] * inv, oacc[dt][t][3] * inv);
                *reinterpret_cast<uint2*>(op + d0) = pk;
            }
        }
    }
}

// ---------------------------------------------------------------------------
// Kernel 3: out = ab(bf16) @ wp^T + proj_b (bf16 MFMA, fp32 out)
// ---------------------------------------------------------------------------
__global__ __launch_bounds__(256) void proj_mfma_kernel(
    const unsigned short* __restrict__ ap, const unsigned short* __restrict__ wpb,
    const float* __restrict__ bias, float* __restrict__ out)
{
    __shared__ __align__(16) unsigned short Xs[128 * 200];
    __shared__ __align__(16) unsigned short Ws[64 * 200];

    const int tid = threadIdx.x;
    const int wgid = blockIdx.x;                  // 768 = 8 XCD * 96
    const int xcd = wgid & 7;
    const int j = wgid >> 3;
    const int bm = (xcd * 32 + (j & 31)) * 128;
    const int bn = (j >> 5) * 64;

    {
        const unsigned short* src = ap + (size_t)(bm + (tid >> 1)) * 192 + (tid & 1) * 96;
        unsigned short* dst = &Xs[(tid >> 1) * 200 + (tid & 1) * 96];
        #pragma unroll
        for (int i = 0; i < 12; ++i)
            *reinterpret_cast<uint4*>(dst + i * 8) =
                *reinterpret_cast<const uint4*>(src + i * 8);
    }
    {
        const unsigned short* src = wpb + (size_t)(bn + (tid >> 2)) * 192 + (tid & 3) * 48;
        unsigned short* dst = &Ws[(tid >> 2) * 200 + (tid & 3) * 48];
        #pragma unroll
        for (int i = 0; i < 6; ++i)
            *reinterpret_cast<uint4*>(dst + i * 8) =
                *reinterpret_cast<const uint4*>(src + i * 8);
    }
    __syncthreads();

    const int w = tid >> 6, l = tid & 63, lq = l & 15, g = l >> 4;
    const int wm = w >> 1, wn = w & 1;

    f32x4 acc[4][2];
    #pragma unroll
    for (int s = 0; s < 4; ++s)
        #pragma unroll
        for (int t = 0; t < 2; ++t)
            acc[s][t] = (f32x4){0.f, 0.f, 0.f, 0.f};

    #pragma unroll
    for (int kk = 0; kk < 6; ++kk) {
        bf16x8 b0 = *reinterpret_cast<const bf16x8*>(
            &Ws[(wn * 32 + lq) * 200 + kk * 32 + g * 8]);
        bf16x8 b1 = *reinterpret_cast<const bf16x8*>(
            &Ws[(wn * 32 + 16 + lq) * 200 + kk * 32 + g * 8]);
        #pragma unroll
        for (int s = 0; s < 4; ++s) {
            bf16x8 a = *reinterpret_cast<const bf16x8*>(
                &Xs[(wm * 64 + s * 16 + lq) * 200 + kk * 32 + g * 8]);
            acc[s][0] = __builtin_amdgcn_mfma_f32_16x16x32_bf16(a, b0, acc[s][0], 0, 0, 0);
            acc[s][1] = __builtin_amdgcn_mfma_f32_16x16x32_bf16(a, b1, acc[s][1], 0, 0, 0);
        }
    }

    #pragma unroll
    for (int s = 0; s < 4; ++s) {
        #pragma unroll
        for (int jr = 0; jr < 4; ++jr) {
            int m = bm + wm * 64 + s * 16 + g * 4 + jr;
            #pragma unroll
            for (int t = 0; t < 2; ++t) {
                int c = bn + wn * 32 + t * 16 + lq;
                out[(size_t)m * 192 + c] = acc[s][t][jr] + bias[c];
            }
        }
    }
}

extern "C" void kernel_launch(void* const* d_in, const int* in_sizes, int n_in,
                              void* d_out, int out_size, void* d_ws, size_t ws_size,
                              hipStream_t stream) {
    const float* x      = (const float*)d_in[0];
    const float* rel    = (const float*)d_in[1];
    const float* maskp  = (const float*)d_in[2];
    const float* qkv_w  = (const float*)d_in[3];
    const float* proj_w = (const float*)d_in[4];
    const float* proj_b = (const float*)d_in[5];
    float* out = (float*)d_out;

    unsigned char* wsb = (unsigned char*)d_ws;
    size_t off = 0;
    unsigned short* xbp  = (unsigned short*)(wsb + off); off += XB_BYTES;
    unsigned short* qbp  = (unsigned short*)(wsb + off); off += QB_BYTES;
    unsigned short* kbp  = (unsigned short*)(wsb + off); off += QB_BYTES;
    unsigned short* vtp  = (unsigned short*)(wsb + off); off += QB_BYTES;
    unsigned short* abp  = (unsigned short*)(wsb + off); off += AB_BYTES;
    unsigned short* wqb  = (unsigned short*)(wsb + off); off += WQ_BYTES;
    unsigned short* wpb  = (unsigned short*)(wsb + off); off += WP_BYTES;
    unsigned short* bias16 = (unsigned short*)(wsb + off); off += BIAS_BYTES;

    // zero Q pads (d=24..31) so padded-K garbage contributes 0 to S
    hipMemsetAsync(qbp, 0, QB_BYTES, stream);

    bias_kernel<<<8192, 256, 0, stream>>>(rel, maskp, bias16);
    convert_kernel<<<6288, 256, 0, stream>>>(x, qkv_w, proj_w, xbp, wqb, wpb);
    qkv_mfma_kernel<<<2304, 256, 0, stream>>>(xbp, wqb, qbp, kbp, vtp);
    attn_mfma_kernel<<<1024, 512, 0, stream>>>(qbp, kbp, vtp, bias16, abp);
    proj_mfma_kernel<<<768, 256, 0, stream>>>(abp, wpb, proj_b, out);
}

// Round 7
// 110.173 us; speedup vs baseline: 4.6306x; 1.0253x over previous
//
#include <hip/hip_runtime.h>
#include <hip/hip_bf16.h>

#define BB 128
#define NN 256
#define CC 192
#define HH 8
#define HD 24
#define HD2 32
#define NWIN 16

typedef __bf16 bf16x8 __attribute__((ext_vector_type(8)));
typedef float f32x4 __attribute__((ext_vector_type(4)));

#define QB_BYTES (size_t)(BB * HH * NN * HD2 * 2)   // 16,777,216
#define AB_BYTES (size_t)(BB * NN * CC * 2)         // 12,582,912
#define BIAS_BYTES (size_t)(128 * NN * NN * 2)      // 16,777,216

// hardware bf16 converts (v_cvt_pk_bf16_f32 / scalar cvt)
__device__ inline unsigned int pkbf(float a, float b) {
    __hip_bfloat162 h = __float22bfloat162_rn(float2{a, b});
    return *reinterpret_cast<unsigned int*>(&h);
}
__device__ inline unsigned short sbf(float a) {
    __hip_bfloat16 h = __float2bfloat16(a);
    return *reinterpret_cast<unsigned short*>(&h);
}

// ---------------------------------------------------------------------------
// Kernel 0: combined bias bias16[c][q][k] = bf16(rel[c>>4] + mask[c&15])
// ---------------------------------------------------------------------------
__global__ __launch_bounds__(256) void bias_kernel(
    const float* __restrict__ rel, const float* __restrict__ maskp,
    unsigned short* __restrict__ bias16)
{
    int idx = blockIdx.x * 256 + threadIdx.x;     // ushort4 units
    int c = idx >> 14;
    int rem = idx & 16383;
    int q = rem >> 6;
    int k4 = rem & 63;
    int h = c >> 4, wi = c & 15;
    float4 rv = *reinterpret_cast<const float4*>(rel + ((size_t)h * NN + q) * NN + k4 * 4);
    float4 mv = *reinterpret_cast<const float4*>(maskp + ((size_t)wi * NN + q) * NN + k4 * 4);
    uint2 o;
    o.x = pkbf(rv.x + mv.x, rv.y + mv.y);
    o.y = pkbf(rv.z + mv.z, rv.w + mv.w);
    *reinterpret_cast<uint2*>(bias16 + ((size_t)c << 16) + q * NN + k4 * 4) = o;
}

// ---------------------------------------------------------------------------
// Kernel 1: qkv = x @ qkv_w.T (bf16 MFMA; fp32 inputs converted in staging).
// Each 64-col tile is pure q, k, or v (192/64=3). Coalesced epilogue via
// LDS transpose: q/k -> U[m][c] row reads; v -> T[c][m] -> 256B v^T rows.
// ---------------------------------------------------------------------------
__global__ __launch_bounds__(256) void qkv_mfma_kernel(
    const float* __restrict__ x, const float* __restrict__ wq,
    unsigned short* __restrict__ qb, unsigned short* __restrict__ kb,
    unsigned short* __restrict__ vt)
{
    __shared__ __align__(16) unsigned short Xs[128 * 200];  // 51200B (reused U/T)
    __shared__ __align__(16) unsigned short Ws[64 * 200];   // 25600B

    const int tid = threadIdx.x;
    const int wgid = blockIdx.x;                  // 2304 = 8 XCD * 288
    const int xcd = wgid & 7;
    const int j = wgid >> 3;
    const int bm = (xcd * 32 + (j & 31)) * 128;
    const int bn = (j >> 5) * 64;

    // stage X tile (fp32 -> bf16): row tid>>1, half tid&1 (96 floats)
    {
        const float* src = x + (size_t)(bm + (tid >> 1)) * 192 + (tid & 1) * 96;
        unsigned short* dst = &Xs[(tid >> 1) * 200 + (tid & 1) * 96];
        #pragma unroll
        for (int i = 0; i < 12; ++i) {
            float4 a = *reinterpret_cast<const float4*>(src + i * 8);
            float4 b = *reinterpret_cast<const float4*>(src + i * 8 + 4);
            uint4 o;
            o.x = pkbf(a.x, a.y); o.y = pkbf(a.z, a.w);
            o.z = pkbf(b.x, b.y); o.w = pkbf(b.z, b.w);
            *reinterpret_cast<uint4*>(dst + i * 8) = o;
        }
    }
    // stage W tile (fp32 -> bf16): row tid>>2, quarter tid&3 (48 floats)
    {
        const float* src = wq + (size_t)(bn + (tid >> 2)) * 192 + (tid & 3) * 48;
        unsigned short* dst = &Ws[(tid >> 2) * 200 + (tid & 3) * 48];
        #pragma unroll
        for (int i = 0; i < 6; ++i) {
            float4 a = *reinterpret_cast<const float4*>(src + i * 8);
            float4 b = *reinterpret_cast<const float4*>(src + i * 8 + 4);
            uint4 o;
            o.x = pkbf(a.x, a.y); o.y = pkbf(a.z, a.w);
            o.z = pkbf(b.x, b.y); o.w = pkbf(b.z, b.w);
            *reinterpret_cast<uint4*>(dst + i * 8) = o;
        }
    }
    __syncthreads();

    const int w = tid >> 6, l = tid & 63, lq = l & 15, g = l >> 4;
    const int wm = w >> 1, wn = w & 1;

    f32x4 acc[4][2];
    #pragma unroll
    for (int s = 0; s < 4; ++s)
        #pragma unroll
        for (int t = 0; t < 2; ++t)
            acc[s][t] = (f32x4){0.f, 0.f, 0.f, 0.f};

    #pragma unroll
    for (int kk = 0; kk < 6; ++kk) {
        bf16x8 b0 = *reinterpret_cast<const bf16x8*>(
            &Ws[(wn * 32 + lq) * 200 + kk * 32 + g * 8]);
        bf16x8 b1 = *reinterpret_cast<const bf16x8*>(
            &Ws[(wn * 32 + 16 + lq) * 200 + kk * 32 + g * 8]);
        #pragma unroll
        for (int s = 0; s < 4; ++s) {
            bf16x8 a = *reinterpret_cast<const bf16x8*>(
                &Xs[(wm * 64 + s * 16 + lq) * 200 + kk * 32 + g * 8]);
            acc[s][0] = __builtin_amdgcn_mfma_f32_16x16x32_bf16(a, b0, acc[s][0], 0, 0, 0);
            acc[s][1] = __builtin_amdgcn_mfma_f32_16x16x32_bf16(a, b1, acc[s][1], 0, 0, 0);
        }
    }

    __syncthreads();   // all waves done reading Xs/Ws before reuse

    const int t3 = bn / 192;          // tile is pure q (0), k (1) or v (2)
    const int bnm = bn - t3 * 192;    // 0, 64, 128
    const int bbi = bm >> 8;

    if (t3 < 2) {
        // ---- path A: U[m_local][c_local], stride 72 ushorts
        const float sc = (t3 == 0) ? 0.20412414523193154f : 1.0f;
        #pragma unroll
        for (int s = 0; s < 4; ++s)
            #pragma unroll
            for (int t = 0; t < 2; ++t)
                #pragma unroll
                for (int jr = 0; jr < 4; ++jr) {
                    int ml = wm * 64 + s * 16 + g * 4 + jr;
                    int cl = wn * 32 + t * 16 + lq;
                    Xs[ml * 72 + cl] = sbf(acc[s][t][jr] * sc);
                }
        __syncthreads();
        unsigned short* dstb = (t3 == 0) ? qb : kb;
        #pragma unroll
        for (int i = 0; i < 8; ++i) {
            int idx = i * 256 + tid;
            int row = idx >> 4, quad = (idx & 15) * 4;
            int cg = bnm + quad;
            int h = cg / 24;
            int d = cg - h * 24;
            int m = bm + row;
            int n = m & 255;
            uint2 v = *reinterpret_cast<const uint2*>(&Xs[row * 72 + quad]);
            *reinterpret_cast<uint2*>(
                &dstb[(((size_t)(bbi * 8 + h) * 256) + n) * 32 + d]) = v;
        }
    } else {
        // ---- path B: T[c_local][m_local], stride 136; jr's are consecutive n
        #pragma unroll
        for (int s = 0; s < 4; ++s)
            #pragma unroll
            for (int t = 0; t < 2; ++t) {
                int cl = wn * 32 + t * 16 + lq;
                int m0 = wm * 64 + s * 16 + g * 4;
                uint2 pk2;
                pk2.x = pkbf(acc[s][t][0], acc[s][t][1]);
                pk2.y = pkbf(acc[s][t][2], acc[s][t][3]);
                *reinterpret_cast<uint2*>(&Xs[cl * 136 + m0]) = pk2;
            }
        __syncthreads();
        const int n0 = bm & 255;
        // FIXED (r6 bug): full coverage = 64 rows x 16 x uint4 (8 ushorts)
        #pragma unroll
        for (int i = 0; i < 4; ++i) {
            int idx = i * 256 + tid;
            int row = idx >> 4, q8 = (idx & 15) * 8;
            int cg = bnm + row;
            int h = cg / 24, d = cg - h * 24;
            uint4 v = *reinterpret_cast<const uint4*>(&Xs[row * 136 + q8]);
            *reinterpret_cast<uint4*>(
                &vt[((size_t)((bbi * 8 + h) * 32) + d) * 256 + n0 + q8]) = v;
        }
    }
}

// ---------------------------------------------------------------------------
// Kernel 2: flash-style MFMA attention. LDS = 54016B -> 3 blocks/CU.
// V in LDS trimmed to 24 real rows; P bounced in 32-k halves.
// ---------------------------------------------------------------------------
#define KSTR 40
#define VROWS 24
#define VSTR 272
#define PSTR 40

__global__ __launch_bounds__(512) void attn_mfma_kernel(
    const unsigned short* __restrict__ qb, const unsigned short* __restrict__ kb,
    const unsigned short* __restrict__ vt,
    const unsigned short* __restrict__ bias16,
    unsigned short* __restrict__ ab)
{
    __shared__ __align__(16) unsigned short Kl[NN * KSTR];        // 20480 B
    __shared__ __align__(16) unsigned short Vl[VROWS * VSTR];     // 13056 B
    __shared__ __align__(16) unsigned short Pw[8][32 * PSTR];     // 20480 B

    const int tid = threadIdx.x;
    const int w  = tid >> 6;
    const int l  = tid & 63;
    const int lq = l & 15;
    const int g  = l >> 4;
    const int wgid = blockIdx.x;
    const int c = wgid & 127;          // bias combo = h*16 + wi (XCD-local)
    const int j = wgid >> 7;
    const int h = c >> 4;
    const int b = (c & 15) + (j << 4);

    const unsigned short* kp = kb + (size_t)(b * HH + h) * NN * HD2;
    const unsigned short* vp = vt + (size_t)(b * HH + h) * HD2 * NN;
    const unsigned short* qp = qb + (size_t)(b * HH + h) * NN * HD2;
    const unsigned short* bp = bias16 + ((size_t)c << 16);

    for (int i = tid; i < 1024; i += 512) {
        int r = i >> 2, cc = i & 3;
        *reinterpret_cast<uint4*>(&Kl[r * KSTR + cc * 8]) =
            *reinterpret_cast<const uint4*>(kp + r * HD2 + cc * 8);
    }
    for (int i = tid; i < 768; i += 512) {
        int r = i >> 5, cc = i & 31;
        *reinterpret_cast<uint4*>(&Vl[r * VSTR + cc * 8]) =
            *reinterpret_cast<const uint4*>(vp + r * NN + cc * 8);
    }

    bf16x8 qf[2];
    #pragma unroll
    for (int t = 0; t < 2; ++t)
        qf[t] = *reinterpret_cast<const bf16x8*>(
            qp + (w * 32 + t * 16 + lq) * HD2 + g * 8);

    const unsigned short* bq0 = bp + (size_t)(w * 32 + lq) * NN;
    const unsigned short* bq1 = bp + (size_t)(w * 32 + 16 + lq) * NN;

    __syncthreads();

    float m_run[2] = {-3.0e38f, -3.0e38f};
    float s_run[2] = {0.f, 0.f};
    f32x4 oacc[2][2];                  // [dt][t]
    #pragma unroll
    for (int dt = 0; dt < 2; ++dt)
        #pragma unroll
        for (int t = 0; t < 2; ++t)
            oacc[dt][t] = (f32x4){0.f, 0.f, 0.f, 0.f};

    for (int kt = 0; kt < 4; ++kt) {
        // ---- QK^T tile
        f32x4 acc[2][4];
        #pragma unroll
        for (int t = 0; t < 2; ++t)
            #pragma unroll
            for (int f = 0; f < 4; ++f)
                acc[t][f] = (f32x4){0.f, 0.f, 0.f, 0.f};
        #pragma unroll
        for (int f = 0; f < 4; ++f) {
            bf16x8 kf = *reinterpret_cast<const bf16x8*>(
                &Kl[(kt * 64 + f * 16 + lq) * KSTR + g * 8]);
            acc[0][f] = __builtin_amdgcn_mfma_f32_16x16x32_bf16(kf, qf[0], acc[0][f], 0, 0, 0);
            acc[1][f] = __builtin_amdgcn_mfma_f32_16x16x32_bf16(kf, qf[1], acc[1][f], 0, 0, 0);
        }

        // ---- bias add
        #pragma unroll
        for (int t = 0; t < 2; ++t) {
            const unsigned short* bq = t ? bq1 : bq0;
            #pragma unroll
            for (int f = 0; f < 4; ++f) {
                uint2 bv = *reinterpret_cast<const uint2*>(bq + kt * 64 + f * 16 + g * 4);
                acc[t][f][0] += __uint_as_float(bv.x << 16);
                acc[t][f][1] += __uint_as_float(bv.x & 0xffff0000u);
                acc[t][f][2] += __uint_as_float(bv.y << 16);
                acc[t][f][3] += __uint_as_float(bv.y & 0xffff0000u);
            }
        }

        // ---- online softmax update (exact, fp32)
        #pragma unroll
        for (int t = 0; t < 2; ++t) {
            float tm = -3.0e38f;
            #pragma unroll
            for (int f = 0; f < 4; ++f)
                #pragma unroll
                for (int jr = 0; jr < 4; ++jr)
                    tm = fmaxf(tm, acc[t][f][jr]);
            tm = fmaxf(tm, __shfl_xor(tm, 16));
            tm = fmaxf(tm, __shfl_xor(tm, 32));
            float m_new = fmaxf(m_run[t], tm);
            float r = __expf(m_run[t] - m_new);
            float ssum = 0.f;
            #pragma unroll
            for (int f = 0; f < 4; ++f)
                #pragma unroll
                for (int jr = 0; jr < 4; ++jr) {
                    float e = __expf(acc[t][f][jr] - m_new);
                    acc[t][f][jr] = e;
                    ssum += e;
                }
            ssum += __shfl_xor(ssum, 16);
            ssum += __shfl_xor(ssum, 32);
            s_run[t] = s_run[t] * r + ssum;
            m_run[t] = m_new;
            #pragma unroll
            for (int dt = 0; dt < 2; ++dt) {
                oacc[dt][t][0] *= r; oacc[dt][t][1] *= r;
                oacc[dt][t][2] *= r; oacc[dt][t][3] *= r;
            }
        }

        // ---- PV in two 32-k halves through per-wave LDS bounce
        #pragma unroll
        for (int k2 = 0; k2 < 2; ++k2) {
            #pragma unroll
            for (int t = 0; t < 2; ++t)
                #pragma unroll
                for (int f2 = 0; f2 < 2; ++f2) {
                    int f = k2 * 2 + f2;
                    uint2 pk;
                    pk.x = pkbf(acc[t][f][0], acc[t][f][1]);
                    pk.y = pkbf(acc[t][f][2], acc[t][f][3]);
                    *reinterpret_cast<uint2*>(
                        &Pw[w][(t * 16 + lq) * PSTR + f2 * 16 + g * 4]) = pk;
                }
            __asm__ volatile("s_waitcnt lgkmcnt(0)" ::: "memory");
            bf16x8 bp0 = *reinterpret_cast<const bf16x8*>(
                &Pw[w][(0 * 16 + lq) * PSTR + g * 8]);
            bf16x8 bp1 = *reinterpret_cast<const bf16x8*>(
                &Pw[w][(1 * 16 + lq) * PSTR + g * 8]);
            #pragma unroll
            for (int dt = 0; dt < 2; ++dt) {
                int vrow = dt * 16 + lq;
                bf16x8 av = {};
                if (vrow < VROWS)
                    av = *reinterpret_cast<const bf16x8*>(
                        &Vl[vrow * VSTR + kt * 64 + k2 * 32 + g * 8]);
                oacc[dt][0] = __builtin_amdgcn_mfma_f32_16x16x32_bf16(av, bp0, oacc[dt][0], 0, 0, 0);
                oacc[dt][1] = __builtin_amdgcn_mfma_f32_16x16x32_bf16(av, bp1, oacc[dt][1], 0, 0, 0);
            }
        }
    }

    // ---- epilogue: out[q][h*24+d] = oacc / s_run, bf16
    #pragma unroll
    for (int t = 0; t < 2; ++t) {
        float inv = 1.0f / s_run[t];
        int qg = b * NN + w * 32 + t * 16 + lq;
        unsigned short* op = ab + (size_t)qg * CC + h * HD;
        #pragma unroll
        for (int dt = 0; dt < 2; ++dt) {
            int d0 = dt * 16 + g * 4;
            if (d0 < HD) {
                uint2 pk;
                pk.x = pkbf(oacc[dt][t][0] * inv, oacc[dt][t][1] * inv);
                pk.y = pkbf(oacc[dt][t][2] * inv, oacc[dt][t][3] * inv);
                *reinterpret_cast<uint2*>(op + d0) = pk;
            }
        }
    }
}

// ---------------------------------------------------------------------------
// Kernel 3: out = ab(bf16) @ proj_w^T + proj_b (fp32 W converted in staging)
// ---------------------------------------------------------------------------
__global__ __launch_bounds__(256) void proj_mfma_kernel(
    const unsigned short* __restrict__ ap, const float* __restrict__ wp,
    const float* __restrict__ bias, float* __restrict__ out)
{
    __shared__ __align__(16) unsigned short Xs[128 * 200];
    __shared__ __align__(16) unsigned short Ws[64 * 200];

    const int tid = threadIdx.x;
    const int wgid = blockIdx.x;                  // 768 = 8 XCD * 96
    const int xcd = wgid & 7;
    const int j = wgid >> 3;
    const int bm = (xcd * 32 + (j & 31)) * 128;
    const int bn = (j >> 5) * 64;

    {
        const unsigned short* src = ap + (size_t)(bm + (tid >> 1)) * 192 + (tid & 1) * 96;
        unsigned short* dst = &Xs[(tid >> 1) * 200 + (tid & 1) * 96];
        #pragma unroll
        for (int i = 0; i < 12; ++i)
            *reinterpret_cast<uint4*>(dst + i * 8) =
                *reinterpret_cast<const uint4*>(src + i * 8);
    }
    {
        const float* src = wp + (size_t)(bn + (tid >> 2)) * 192 + (tid & 3) * 48;
        unsigned short* dst = &Ws[(tid >> 2) * 200 + (tid & 3) * 48];
        #pragma unroll
        for (int i = 0; i < 6; ++i) {
            float4 a = *reinterpret_cast<const float4*>(src + i * 8);
            float4 b = *reinterpret_cast<const float4*>(src + i * 8 + 4);
            uint4 o;
            o.x = pkbf(a.x, a.y); o.y = pkbf(a.z, a.w);
            o.z = pkbf(b.x, b.y); o.w = pkbf(b.z, b.w);
            *reinterpret_cast<uint4*>(dst + i * 8) = o;
        }
    }
    __syncthreads();

    const int w = tid >> 6, l = tid & 63, lq = l & 15, g = l >> 4;
    const int wm = w >> 1, wn = w & 1;

    f32x4 acc[4][2];
    #pragma unroll
    for (int s = 0; s < 4; ++s)
        #pragma unroll
        for (int t = 0; t < 2; ++t)
            acc[s][t] = (f32x4){0.f, 0.f, 0.f, 0.f};

    #pragma unroll
    for (int kk = 0; kk < 6; ++kk) {
        bf16x8 b0 = *reinterpret_cast<const bf16x8*>(
            &Ws[(wn * 32 + lq) * 200 + kk * 32 + g * 8]);
        bf16x8 b1 = *reinterpret_cast<const bf16x8*>(
            &Ws[(wn * 32 + 16 + lq) * 200 + kk * 32 + g * 8]);
        #pragma unroll
        for (int s = 0; s < 4; ++s) {
            bf16x8 a = *reinterpret_cast<const bf16x8*>(
                &Xs[(wm * 64 + s * 16 + lq) * 200 + kk * 32 + g * 8]);
            acc[s][0] = __builtin_amdgcn_mfma_f32_16x16x32_bf16(a, b0, acc[s][0], 0, 0, 0);
            acc[s][1] = __builtin_amdgcn_mfma_f32_16x16x32_bf16(a, b1, acc[s][1], 0, 0, 0);
        }
    }

    #pragma unroll
    for (int s = 0; s < 4; ++s) {
        #pragma unroll
        for (int jr = 0; jr < 4; ++jr) {
            int m = bm + wm * 64 + s * 16 + g * 4 + jr;
            #pragma unroll
            for (int t = 0; t < 2; ++t) {
                int c = bn + wn * 32 + t * 16 + lq;
                out[(size_t)m * 192 + c] = acc[s][t][jr] + bias[c];
            }
        }
    }
}

extern "C" void kernel_launch(void* const* d_in, const int* in_sizes, int n_in,
                              void* d_out, int out_size, void* d_ws, size_t ws_size,
                              hipStream_t stream) {
    const float* x      = (const float*)d_in[0];
    const float* rel    = (const float*)d_in[1];
    const float* maskp  = (const float*)d_in[2];
    const float* qkv_w  = (const float*)d_in[3];
    const float* proj_w = (const float*)d_in[4];
    const float* proj_b = (const float*)d_in[5];
    float* out = (float*)d_out;

    unsigned char* wsb = (unsigned char*)d_ws;
    size_t off = 0;
    unsigned short* qbp  = (unsigned short*)(wsb + off); off += QB_BYTES;
    unsigned short* kbp  = (unsigned short*)(wsb + off); off += QB_BYTES;
    unsigned short* vtp  = (unsigned short*)(wsb + off); off += QB_BYTES;
    unsigned short* abp  = (unsigned short*)(wsb + off); off += AB_BYTES;
    unsigned short* bias16 = (unsigned short*)(wsb + off); off += BIAS_BYTES;

    // zero Q pads (d=24..31) so padded-K garbage contributes 0 to S
    hipMemsetAsync(qbp, 0, QB_BYTES, stream);

    bias_kernel<<<8192, 256, 0, stream>>>(rel, maskp, bias16);
    qkv_mfma_kernel<<<2304, 256, 0, stream>>>(x, qkv_w, qbp, kbp, vtp);
    attn_mfma_kernel<<<1024, 512, 0, stream>>>(qbp, kbp, vtp, bias16, abp);
    proj_mfma_kernel<<<768, 256, 0, stream>>>(abp, proj_w, proj_b, out);
}

// Round 8
// 98.584 us; speedup vs baseline: 5.1750x; 1.1176x over previous
//
#include <hip/hip_runtime.h>
#include <hip/hip_bf16.h>

#define BB 128
#define NN 256
#define CC 192
#define HH 8
#define HD 24
#define HD2 32
#define NWIN 16

typedef __bf16 bf16x8 __attribute__((ext_vector_type(8)));
typedef float f32x4 __attribute__((ext_vector_type(4)));

#define QB_BYTES (size_t)(BB * HH * NN * HD2 * 2)   // 16,777,216
#define AB_BYTES (size_t)(BB * NN * CC * 2)         // 12,582,912
#define BIAS_BYTES (size_t)(128 * NN * NN * 2)      // 16,777,216

// hardware bf16 converts (v_cvt_pk_bf16_f32 / scalar cvt)
__device__ inline unsigned int pkbf(float a, float b) {
    __hip_bfloat162 h = __float22bfloat162_rn(float2{a, b});
    return *reinterpret_cast<unsigned int*>(&h);
}
__device__ inline unsigned short sbf(float a) {
    __hip_bfloat16 h = __float2bfloat16(a);
    return *reinterpret_cast<unsigned short*>(&h);
}

// ---------------------------------------------------------------------------
// Kernel 0: combined bias bias16[c][q][k] = bf16(rel[c>>4] + mask[c&15])
// ---------------------------------------------------------------------------
__global__ __launch_bounds__(256) void bias_kernel(
    const float* __restrict__ rel, const float* __restrict__ maskp,
    unsigned short* __restrict__ bias16)
{
    int idx = blockIdx.x * 256 + threadIdx.x;     // ushort4 units
    int c = idx >> 14;
    int rem = idx & 16383;
    int q = rem >> 6;
    int k4 = rem & 63;
    int h = c >> 4, wi = c & 15;
    float4 rv = *reinterpret_cast<const float4*>(rel + ((size_t)h * NN + q) * NN + k4 * 4);
    float4 mv = *reinterpret_cast<const float4*>(maskp + ((size_t)wi * NN + q) * NN + k4 * 4);
    uint2 o;
    o.x = pkbf(rv.x + mv.x, rv.y + mv.y);
    o.y = pkbf(rv.z + mv.z, rv.w + mv.w);
    *reinterpret_cast<uint2*>(bias16 + ((size_t)c << 16) + q * NN + k4 * 4) = o;
}

// ---------------------------------------------------------------------------
// Kernel 1: qkv = x @ qkv_w.T (bf16 MFMA; fp32 converted in staging).
// BK=96 K-split, single-buffered: LDS 39.9KB -> 4 blocks/CU.
// Coalesced epilogue via LDS transpose (reuses Xs).
// ---------------------------------------------------------------------------
#define XSTR 104   // 96 cols + pad, 208B rows (16B aligned)

__global__ __launch_bounds__(256) void qkv_mfma_kernel(
    const float* __restrict__ x, const float* __restrict__ wq,
    unsigned short* __restrict__ qb, unsigned short* __restrict__ kb,
    unsigned short* __restrict__ vt)
{
    __shared__ __align__(16) unsigned short Xs[128 * XSTR];  // 26624B (reused U/T)
    __shared__ __align__(16) unsigned short Ws[64 * XSTR];   // 13312B

    const int tid = threadIdx.x;
    const int wgid = blockIdx.x;                  // 2304 = 8 XCD * 288
    const int xcd = wgid & 7;
    const int j = wgid >> 3;
    const int bm = (xcd * 32 + (j & 31)) * 128;
    const int bn = (j >> 5) * 64;

    const int w = tid >> 6, l = tid & 63, lq = l & 15, g = l >> 4;
    const int wm = w >> 1, wn = w & 1;

    f32x4 acc[4][2];
    #pragma unroll
    for (int s = 0; s < 4; ++s)
        #pragma unroll
        for (int t = 0; t < 2; ++t)
            acc[s][t] = (f32x4){0.f, 0.f, 0.f, 0.f};

    #pragma unroll
    for (int kh = 0; kh < 2; ++kh) {
        // stage X half (fp32 -> bf16): row tid>>1, 48 floats at (tid&1)*48
        {
            const float* src = x + (size_t)(bm + (tid >> 1)) * 192 + kh * 96 + (tid & 1) * 48;
            unsigned short* dst = &Xs[(tid >> 1) * XSTR + (tid & 1) * 48];
            #pragma unroll
            for (int i = 0; i < 6; ++i) {
                float4 a = *reinterpret_cast<const float4*>(src + i * 8);
                float4 b = *reinterpret_cast<const float4*>(src + i * 8 + 4);
                uint4 o;
                o.x = pkbf(a.x, a.y); o.y = pkbf(a.z, a.w);
                o.z = pkbf(b.x, b.y); o.w = pkbf(b.z, b.w);
                *reinterpret_cast<uint4*>(dst + i * 8) = o;
            }
        }
        // stage W half: row tid>>2, 24 floats at (tid&3)*24
        {
            const float* src = wq + (size_t)(bn + (tid >> 2)) * 192 + kh * 96 + (tid & 3) * 24;
            unsigned short* dst = &Ws[(tid >> 2) * XSTR + (tid & 3) * 24];
            #pragma unroll
            for (int i = 0; i < 3; ++i) {
                float4 a = *reinterpret_cast<const float4*>(src + i * 8);
                float4 b = *reinterpret_cast<const float4*>(src + i * 8 + 4);
                uint4 o;
                o.x = pkbf(a.x, a.y); o.y = pkbf(a.z, a.w);
                o.z = pkbf(b.x, b.y); o.w = pkbf(b.z, b.w);
                *reinterpret_cast<uint4*>(dst + i * 8) = o;
            }
        }
        __syncthreads();

        #pragma unroll
        for (int kk = 0; kk < 3; ++kk) {
            bf16x8 b0 = *reinterpret_cast<const bf16x8*>(
                &Ws[(wn * 32 + lq) * XSTR + kk * 32 + g * 8]);
            bf16x8 b1 = *reinterpret_cast<const bf16x8*>(
                &Ws[(wn * 32 + 16 + lq) * XSTR + kk * 32 + g * 8]);
            #pragma unroll
            for (int s = 0; s < 4; ++s) {
                bf16x8 a = *reinterpret_cast<const bf16x8*>(
                    &Xs[(wm * 64 + s * 16 + lq) * XSTR + kk * 32 + g * 8]);
                acc[s][0] = __builtin_amdgcn_mfma_f32_16x16x32_bf16(a, b0, acc[s][0], 0, 0, 0);
                acc[s][1] = __builtin_amdgcn_mfma_f32_16x16x32_bf16(a, b1, acc[s][1], 0, 0, 0);
            }
        }
        __syncthreads();   // done reading this half (also guards Xs reuse)
    }

    const int t3 = bn / 192;          // tile is pure q (0), k (1) or v (2)
    const int bnm = bn - t3 * 192;    // 0, 64, 128
    const int bbi = bm >> 8;

    if (t3 < 2) {
        // ---- path A: U[m_local][c_local], stride 72 ushorts
        const float sc = (t3 == 0) ? 0.20412414523193154f : 1.0f;
        #pragma unroll
        for (int s = 0; s < 4; ++s)
            #pragma unroll
            for (int t = 0; t < 2; ++t)
                #pragma unroll
                for (int jr = 0; jr < 4; ++jr) {
                    int ml = wm * 64 + s * 16 + g * 4 + jr;
                    int cl = wn * 32 + t * 16 + lq;
                    Xs[ml * 72 + cl] = sbf(acc[s][t][jr] * sc);
                }
        __syncthreads();
        unsigned short* dstb = (t3 == 0) ? qb : kb;
        #pragma unroll
        for (int i = 0; i < 8; ++i) {
            int idx = i * 256 + tid;
            int row = idx >> 4, quad = (idx & 15) * 4;
            int cg = bnm + quad;
            int h = cg / 24;
            int d = cg - h * 24;
            int m = bm + row;
            int n = m & 255;
            uint2 v = *reinterpret_cast<const uint2*>(&Xs[row * 72 + quad]);
            *reinterpret_cast<uint2*>(
                &dstb[(((size_t)(bbi * 8 + h) * 256) + n) * 32 + d]) = v;
        }
    } else {
        // ---- path B: T[c_local][m_local], stride 136; jr's are consecutive n
        #pragma unroll
        for (int s = 0; s < 4; ++s)
            #pragma unroll
            for (int t = 0; t < 2; ++t) {
                int cl = wn * 32 + t * 16 + lq;
                int m0 = wm * 64 + s * 16 + g * 4;
                uint2 pk2;
                pk2.x = pkbf(acc[s][t][0], acc[s][t][1]);
                pk2.y = pkbf(acc[s][t][2], acc[s][t][3]);
                *reinterpret_cast<uint2*>(&Xs[cl * 136 + m0]) = pk2;
            }
        __syncthreads();
        const int n0 = bm & 255;
        // full coverage: 64 rows x 16 x uint4 (8 ushorts)
        #pragma unroll
        for (int i = 0; i < 4; ++i) {
            int idx = i * 256 + tid;
            int row = idx >> 4, q8 = (idx & 15) * 8;
            int cg = bnm + row;
            int h = cg / 24, d = cg - h * 24;
            uint4 v = *reinterpret_cast<const uint4*>(&Xs[row * 136 + q8]);
            *reinterpret_cast<uint4*>(
                &vt[((size_t)((bbi * 8 + h) * 32) + d) * 256 + n0 + q8]) = v;
        }
    }
}

// ---------------------------------------------------------------------------
// Kernel 2: flash-style MFMA attention. LDS = 54016B -> 3 blocks/CU.
// Q pads handled in-register (g==3 chunk zeroed) -> no memset needed.
// ---------------------------------------------------------------------------
#define KSTR 40
#define VROWS 24
#define VSTR 272
#define PSTR 40

__global__ __launch_bounds__(512) void attn_mfma_kernel(
    const unsigned short* __restrict__ qb, const unsigned short* __restrict__ kb,
    const unsigned short* __restrict__ vt,
    const unsigned short* __restrict__ bias16,
    unsigned short* __restrict__ ab)
{
    __shared__ __align__(16) unsigned short Kl[NN * KSTR];        // 20480 B
    __shared__ __align__(16) unsigned short Vl[VROWS * VSTR];     // 13056 B
    __shared__ __align__(16) unsigned short Pw[8][32 * PSTR];     // 20480 B

    const int tid = threadIdx.x;
    const int w  = tid >> 6;
    const int l  = tid & 63;
    const int lq = l & 15;
    const int g  = l >> 4;
    const int wgid = blockIdx.x;
    const int c = wgid & 127;          // bias combo = h*16 + wi (XCD-local)
    const int j = wgid >> 7;
    const int h = c >> 4;
    const int b = (c & 15) + (j << 4);

    const unsigned short* kp = kb + (size_t)(b * HH + h) * NN * HD2;
    const unsigned short* vp = vt + (size_t)(b * HH + h) * HD2 * NN;
    const unsigned short* qp = qb + (size_t)(b * HH + h) * NN * HD2;
    const unsigned short* bp = bias16 + ((size_t)c << 16);

    for (int i = tid; i < 1024; i += 512) {
        int r = i >> 2, cc = i & 3;
        *reinterpret_cast<uint4*>(&Kl[r * KSTR + cc * 8]) =
            *reinterpret_cast<const uint4*>(kp + r * HD2 + cc * 8);
    }
    for (int i = tid; i < 768; i += 512) {
        int r = i >> 5, cc = i & 31;
        *reinterpret_cast<uint4*>(&Vl[r * VSTR + cc * 8]) =
            *reinterpret_cast<const uint4*>(vp + r * NN + cc * 8);
    }

    // Q fragment; g==3 chunk (d=24..31) zeroed in-register so K-pad garbage
    // multiplies zero -> no need to ever initialize the pad memory.
    bf16x8 qf[2];
    #pragma unroll
    for (int t = 0; t < 2; ++t) {
        bf16x8 z = {};
        qf[t] = (g == 3) ? z : *reinterpret_cast<const bf16x8*>(
            qp + (w * 32 + t * 16 + lq) * HD2 + g * 8);
    }

    const unsigned short* bq0 = bp + (size_t)(w * 32 + lq) * NN;
    const unsigned short* bq1 = bp + (size_t)(w * 32 + 16 + lq) * NN;

    __syncthreads();

    float m_run[2] = {-3.0e38f, -3.0e38f};
    float s_run[2] = {0.f, 0.f};
    f32x4 oacc[2][2];                  // [dt][t]
    #pragma unroll
    for (int dt = 0; dt < 2; ++dt)
        #pragma unroll
        for (int t = 0; t < 2; ++t)
            oacc[dt][t] = (f32x4){0.f, 0.f, 0.f, 0.f};

    for (int kt = 0; kt < 4; ++kt) {
        // ---- QK^T tile
        f32x4 acc[2][4];
        #pragma unroll
        for (int t = 0; t < 2; ++t)
            #pragma unroll
            for (int f = 0; f < 4; ++f)
                acc[t][f] = (f32x4){0.f, 0.f, 0.f, 0.f};
        #pragma unroll
        for (int f = 0; f < 4; ++f) {
            bf16x8 kf = *reinterpret_cast<const bf16x8*>(
                &Kl[(kt * 64 + f * 16 + lq) * KSTR + g * 8]);
            acc[0][f] = __builtin_amdgcn_mfma_f32_16x16x32_bf16(kf, qf[0], acc[0][f], 0, 0, 0);
            acc[1][f] = __builtin_amdgcn_mfma_f32_16x16x32_bf16(kf, qf[1], acc[1][f], 0, 0, 0);
        }

        // ---- bias add
        #pragma unroll
        for (int t = 0; t < 2; ++t) {
            const unsigned short* bq = t ? bq1 : bq0;
            #pragma unroll
            for (int f = 0; f < 4; ++f) {
                uint2 bv = *reinterpret_cast<const uint2*>(bq + kt * 64 + f * 16 + g * 4);
                acc[t][f][0] += __uint_as_float(bv.x << 16);
                acc[t][f][1] += __uint_as_float(bv.x & 0xffff0000u);
                acc[t][f][2] += __uint_as_float(bv.y << 16);
                acc[t][f][3] += __uint_as_float(bv.y & 0xffff0000u);
            }
        }

        // ---- online softmax update (exact, fp32)
        #pragma unroll
        for (int t = 0; t < 2; ++t) {
            float tm = -3.0e38f;
            #pragma unroll
            for (int f = 0; f < 4; ++f)
                #pragma unroll
                for (int jr = 0; jr < 4; ++jr)
                    tm = fmaxf(tm, acc[t][f][jr]);
            tm = fmaxf(tm, __shfl_xor(tm, 16));
            tm = fmaxf(tm, __shfl_xor(tm, 32));
            float m_new = fmaxf(m_run[t], tm);
            float r = __expf(m_run[t] - m_new);
            float ssum = 0.f;
            #pragma unroll
            for (int f = 0; f < 4; ++f)
                #pragma unroll
                for (int jr = 0; jr < 4; ++jr) {
                    float e = __expf(acc[t][f][jr] - m_new);
                    acc[t][f][jr] = e;
                    ssum += e;
                }
            ssum += __shfl_xor(ssum, 16);
            ssum += __shfl_xor(ssum, 32);
            s_run[t] = s_run[t] * r + ssum;
            m_run[t] = m_new;
            #pragma unroll
            for (int dt = 0; dt < 2; ++dt) {
                oacc[dt][t][0] *= r; oacc[dt][t][1] *= r;
                oacc[dt][t][2] *= r; oacc[dt][t][3] *= r;
            }
        }

        // ---- PV in two 32-k halves through per-wave LDS bounce
        #pragma unroll
        for (int k2 = 0; k2 < 2; ++k2) {
            #pragma unroll
            for (int t = 0; t < 2; ++t)
                #pragma unroll
                for (int f2 = 0; f2 < 2; ++f2) {
                    int f = k2 * 2 + f2;
                    uint2 pk;
                    pk.x = pkbf(acc[t][f][0], acc[t][f][1]);
                    pk.y = pkbf(acc[t][f][2], acc[t][f][3]);
                    *reinterpret_cast<uint2*>(
                        &Pw[w][(t * 16 + lq) * PSTR + f2 * 16 + g * 4]) = pk;
                }
            __asm__ volatile("s_waitcnt lgkmcnt(0)" ::: "memory");
            bf16x8 bp0 = *reinterpret_cast<const bf16x8*>(
                &Pw[w][(0 * 16 + lq) * PSTR + g * 8]);
            bf16x8 bp1 = *reinterpret_cast<const bf16x8*>(
                &Pw[w][(1 * 16 + lq) * PSTR + g * 8]);
            #pragma unroll
            for (int dt = 0; dt < 2; ++dt) {
                int vrow = dt * 16 + lq;
                bf16x8 av = {};
                if (vrow < VROWS)
                    av = *reinterpret_cast<const bf16x8*>(
                        &Vl[vrow * VSTR + kt * 64 + k2 * 32 + g * 8]);
                oacc[dt][0] = __builtin_amdgcn_mfma_f32_16x16x32_bf16(av, bp0, oacc[dt][0], 0, 0, 0);
                oacc[dt][1] = __builtin_amdgcn_mfma_f32_16x16x32_bf16(av, bp1, oacc[dt][1], 0, 0, 0);
            }
        }
    }

    // ---- epilogue: out[q][h*24+d] = oacc / s_run, bf16
    #pragma unroll
    for (int t = 0; t < 2; ++t) {
        float inv = 1.0f / s_run[t];
        int qg = b * NN + w * 32 + t * 16 + lq;
        unsigned short* op = ab + (size_t)qg * CC + h * HD;
        #pragma unroll
        for (int dt = 0; dt < 2; ++dt) {
            int d0 = dt * 16 + g * 4;
            if (d0 < HD) {
                uint2 pk;
                pk.x = pkbf(oacc[dt][t][0] * inv, oacc[dt][t][1] * inv);
                pk.y = pkbf(oacc[dt][t][2] * inv, oacc[dt][t][3] * inv);
                *reinterpret_cast<uint2*>(op + d0) = pk;
            }
        }
    }
}

// ---------------------------------------------------------------------------
// Kernel 3: out = ab(bf16) @ proj_w^T + proj_b. BK=96 split -> 4 blocks/CU.
// ---------------------------------------------------------------------------
__global__ __launch_bounds__(256) void proj_mfma_kernel(
    const unsigned short* __restrict__ ap, const float* __restrict__ wp,
    const float* __restrict__ bias, float* __restrict__ out)
{
    __shared__ __align__(16) unsigned short Xs[128 * XSTR];
    __shared__ __align__(16) unsigned short Ws[64 * XSTR];

    const int tid = threadIdx.x;
    const int wgid = blockIdx.x;                  // 768 = 8 XCD * 96
    const int xcd = wgid & 7;
    const int j = wgid >> 3;
    const int bm = (xcd * 32 + (j & 31)) * 128;
    const int bn = (j >> 5) * 64;

    const int w = tid >> 6, l = tid & 63, lq = l & 15, g = l >> 4;
    const int wm = w >> 1, wn = w & 1;

    f32x4 acc[4][2];
    #pragma unroll
    for (int s = 0; s < 4; ++s)
        #pragma unroll
        for (int t = 0; t < 2; ++t)
            acc[s][t] = (f32x4){0.f, 0.f, 0.f, 0.f};

    #pragma unroll
    for (int kh = 0; kh < 2; ++kh) {
        // stage A half (bf16 copy): row tid>>1, 48 ushorts at (tid&1)*48
        {
            const unsigned short* src = ap + (size_t)(bm + (tid >> 1)) * 192 + kh * 96 + (tid & 1) * 48;
            unsigned short* dst = &Xs[(tid >> 1) * XSTR + (tid & 1) * 48];
            #pragma unroll
            for (int i = 0; i < 6; ++i)
                *reinterpret_cast<uint4*>(dst + i * 8) =
                    *reinterpret_cast<const uint4*>(src + i * 8);
        }
        // stage W half (fp32 -> bf16): row tid>>2, 24 floats at (tid&3)*24
        {
            const float* src = wp + (size_t)(bn + (tid >> 2)) * 192 + kh * 96 + (tid & 3) * 24;
            unsigned short* dst = &Ws[(tid >> 2) * XSTR + (tid & 3) * 24];
            #pragma unroll
            for (int i = 0; i < 3; ++i) {
                float4 a = *reinterpret_cast<const float4*>(src + i * 8);
                float4 b = *reinterpret_cast<const float4*>(src + i * 8 + 4);
                uint4 o;
                o.x = pkbf(a.x, a.y); o.y = pkbf(a.z, a.w);
                o.z = pkbf(b.x, b.y); o.w = pkbf(b.z, b.w);
                *reinterpret_cast<uint4*>(dst + i * 8) = o;
            }
        }
        __syncthreads();

        #pragma unroll
        for (int kk = 0; kk < 3; ++kk) {
            bf16x8 b0 = *reinterpret_cast<const bf16x8*>(
                &Ws[(wn * 32 + lq) * XSTR + kk * 32 + g * 8]);
            bf16x8 b1 = *reinterpret_cast<const bf16x8*>(
                &Ws[(wn * 32 + 16 + lq) * XSTR + kk * 32 + g * 8]);
            #pragma unroll
            for (int s = 0; s < 4; ++s) {
                bf16x8 a = *reinterpret_cast<const bf16x8*>(
                    &Xs[(wm * 64 + s * 16 + lq) * XSTR + kk * 32 + g * 8]);
                acc[s][0] = __builtin_amdgcn_mfma_f32_16x16x32_bf16(a, b0, acc[s][0], 0, 0, 0);
                acc[s][1] = __builtin_amdgcn_mfma_f32_16x16x32_bf16(a, b1, acc[s][1], 0, 0, 0);
            }
        }
        __syncthreads();
    }

    #pragma unroll
    for (int s = 0; s < 4; ++s) {
        #pragma unroll
        for (int jr = 0; jr < 4; ++jr) {
            int m = bm + wm * 64 + s * 16 + g * 4 + jr;
            #pragma unroll
            for (int t = 0; t < 2; ++t) {
                int c = bn + wn * 32 + t * 16 + lq;
                out[(size_t)m * 192 + c] = acc[s][t][jr] + bias[c];
            }
        }
    }
}

extern "C" void kernel_launch(void* const* d_in, const int* in_sizes, int n_in,
                              void* d_out, int out_size, void* d_ws, size_t ws_size,
                              hipStream_t stream) {
    const float* x      = (const float*)d_in[0];
    const float* rel    = (const float*)d_in[1];
    const float* maskp  = (const float*)d_in[2];
    const float* qkv_w  = (const float*)d_in[3];
    const float* proj_w = (const float*)d_in[4];
    const float* proj_b = (const float*)d_in[5];
    float* out = (float*)d_out;

    unsigned char* wsb = (unsigned char*)d_ws;
    size_t off = 0;
    unsigned short* qbp  = (unsigned short*)(wsb + off); off += QB_BYTES;
    unsigned short* kbp  = (unsigned short*)(wsb + off); off += QB_BYTES;
    unsigned short* vtp  = (unsigned short*)(wsb + off); off += QB_BYTES;
    unsigned short* abp  = (unsigned short*)(wsb + off); off += AB_BYTES;
    unsigned short* bias16 = (unsigned short*)(wsb + off); off += BIAS_BYTES;

    bias_kernel<<<8192, 256, 0, stream>>>(rel, maskp, bias16);
    qkv_mfma_kernel<<<2304, 256, 0, stream>>>(x, qkv_w, qbp, kbp, vtp);
    attn_mfma_kernel<<<1024, 512, 0, stream>>>(qbp, kbp, vtp, bias16, abp);
    proj_mfma_kernel<<<768, 256, 0, stream>>>(abp, proj_w, proj_b, out);
}